// Round 1
// 976.113 us; speedup vs baseline: 9.6318x; 9.6318x over previous
//
#include <hip/hip_runtime.h>
#include <math.h>

typedef unsigned short u16;
typedef __attribute__((ext_vector_type(8))) short short8;
typedef __attribute__((ext_vector_type(8))) _Float16 half8;
typedef __attribute__((ext_vector_type(4))) float floatx4;

#define NH 16
#define NKV 8
#define HD 256
#define SEQ 2048
#define BATCH 2
#define QD (NH * HD)    // 4096
#define KVD (NKV * HD)  // 2048
#define TOKS (BATCH * SEQ)  // 4096
#define WINDOW 1024

__device__ __forceinline__ u16 f2h(float f) {
    _Float16 h = (_Float16)f;
    return __builtin_bit_cast(u16, h);
}
__device__ __forceinline__ float h2f(u16 u) {
    return (float)__builtin_bit_cast(_Float16, u);
}

// load 8 contiguous elements as f16 bits (converting from f32 if F32)
template<bool F32>
__device__ __forceinline__ short8 load8(const void* p, size_t idx) {
    if constexpr (F32) {
        const float* f = (const float*)p + idx;
        float4 a = *(const float4*)(f);
        float4 b = *(const float4*)(f + 4);
        short8 r;
        r[0] = (short)f2h(a.x); r[1] = (short)f2h(a.y);
        r[2] = (short)f2h(a.z); r[3] = (short)f2h(a.w);
        r[4] = (short)f2h(b.x); r[5] = (short)f2h(b.y);
        r[6] = (short)f2h(b.z); r[7] = (short)f2h(b.w);
        return r;
    } else {
        return *(const short8*)((const u16*)p + idx);
    }
}

// ---------------------------------------------------------------------------
// GEMM: C[M,N] = A[M,K] * B[N,K]^T, fp32 accum, f16 MFMA internally.
// A/B f32 (converted on stage) or f16-bits; C written f32 (OUTF32) or f16.
// OUTT: store C transposed (C^T[N][M], f16 only) -- used to produce V^T.
// 128x128 tile, BK=32, 256 threads = 4 waves, each wave 64x64 (4x4 MFMA).
// ---------------------------------------------------------------------------
template<bool AF32, bool BF32, bool OUTF32, bool OUTT>
__global__ __launch_bounds__(256) void gemm_bt(const void* __restrict__ Ap,
                                               const void* __restrict__ Bp,
                                               void* __restrict__ Cp,
                                               int M, int N, int K) {
    constexpr int LDA = 40;  // 32 + 8 pad; row stride 80B, 16B aligned
    __shared__ u16 As[128 * LDA];
    __shared__ u16 Bs[128 * LDA];

    const int tid = threadIdx.x;
    const int wave = tid >> 6, lane = tid & 63;
    const int quad = lane >> 4, l16 = lane & 15;
    const int bm = blockIdx.y * 128, bn = blockIdx.x * 128;
    const int wm = (wave >> 1) * 64, wn = (wave & 1) * 64;
    const int srow = tid >> 2;          // 0..63
    const int scol = (tid & 3) * 8;     // 0,8,16,24

    floatx4 acc[4][4];
#pragma unroll
    for (int i = 0; i < 4; ++i)
#pragma unroll
        for (int j = 0; j < 4; ++j) acc[i][j] = (floatx4){0.f, 0.f, 0.f, 0.f};

    const int kTiles = K >> 5;
    for (int kt = 0; kt < kTiles; ++kt) {
        const int k0 = kt << 5;
        short8 a0 = load8<AF32>(Ap, (size_t)(bm + srow) * K + k0 + scol);
        short8 a1 = load8<AF32>(Ap, (size_t)(bm + 64 + srow) * K + k0 + scol);
        short8 b0 = load8<BF32>(Bp, (size_t)(bn + srow) * K + k0 + scol);
        short8 b1 = load8<BF32>(Bp, (size_t)(bn + 64 + srow) * K + k0 + scol);
        __syncthreads();  // previous iteration's LDS reads complete
        *(short8*)(&As[srow * LDA + scol]) = a0;
        *(short8*)(&As[(64 + srow) * LDA + scol]) = a1;
        *(short8*)(&Bs[srow * LDA + scol]) = b0;
        *(short8*)(&Bs[(64 + srow) * LDA + scol]) = b1;
        __syncthreads();

        half8 af[4], bfr[4];
#pragma unroll
        for (int i = 0; i < 4; ++i)
            af[i] = *(const half8*)(&As[(wm + i * 16 + l16) * LDA + quad * 8]);
#pragma unroll
        for (int j = 0; j < 4; ++j)
            bfr[j] = *(const half8*)(&Bs[(wn + j * 16 + l16) * LDA + quad * 8]);
#pragma unroll
        for (int i = 0; i < 4; ++i)
#pragma unroll
            for (int j = 0; j < 4; ++j)
                acc[i][j] = __builtin_amdgcn_mfma_f32_16x16x32_f16(af[i], bfr[j], acc[i][j], 0, 0, 0);
    }

    // epilogue: C row = bm+wm+i*16+quad*4+r, col = bn+wn+j*16+l16
#pragma unroll
    for (int i = 0; i < 4; ++i) {
#pragma unroll
        for (int j = 0; j < 4; ++j) {
            const int row0 = bm + wm + i * 16 + quad * 4;
            const int col = bn + wn + j * 16 + l16;
#pragma unroll
            for (int r = 0; r < 4; ++r) {
                if constexpr (OUTT)
                    ((u16*)Cp)[(size_t)col * M + row0 + r] = f2h(acc[i][j][r]);
                else if constexpr (OUTF32)
                    ((float*)Cp)[(size_t)(row0 + r) * N + col] = acc[i][j][r];
                else
                    ((u16*)Cp)[(size_t)(row0 + r) * N + col] = f2h(acc[i][j][r]);
            }
        }
    }
}

// ---------------------------------------------------------------------------
// Fused per-head RMSNorm (+weight) and RoPE for Q and K. One wave per
// (row, head-slot). slots: 0..15 Q heads, 16..23 K heads. In-place (f16).
// ---------------------------------------------------------------------------
__global__ __launch_bounds__(256) void norm_rope_kernel(
        u16* __restrict__ Q, u16* __restrict__ K,
        const float* __restrict__ qw, const float* __restrict__ kw,
        const float* __restrict__ cosp, const float* __restrict__ sinp) {
    const int w = blockIdx.x * 4 + (threadIdx.x >> 6);
    const int lane = threadIdx.x & 63;
    const int row = w >> 5;   // 0..4095 (= b*2048+s)
    const int sub = w & 31;
    if (sub >= 24) return;    // V handled by vnorm_kernel on V^T

    u16* ptr;
    const float* wt;
    if (sub < 16) { ptr = Q + (size_t)row * QD + sub * HD;         wt = qw; }
    else          { ptr = K + (size_t)row * KVD + (sub - 16) * HD; wt = kw; }

    const int d = lane * 4;
    uint2 raw = *(const uint2*)(ptr + d);
    float x[4];
    x[0] = h2f((u16)(raw.x & 0xffffu));
    x[1] = h2f((u16)(raw.x >> 16));
    x[2] = h2f((u16)(raw.y & 0xffffu));
    x[3] = h2f((u16)(raw.y >> 16));

    float ss = x[0] * x[0] + x[1] * x[1] + x[2] * x[2] + x[3] * x[3];
#pragma unroll
    for (int m = 1; m < 64; m <<= 1) ss += __shfl_xor(ss, m, 64);
    const float sc = rsqrtf(ss * (1.0f / 256.0f) + 1e-6f);

    float nrm[4];
#pragma unroll
    for (int i = 0; i < 4; ++i) nrm[i] = x[i] * sc * wt[d + i];

    const size_t cbase = (size_t)row * HD + d;
    const float sgn = (lane < 32) ? -1.0f : 1.0f;
    float out[4];
#pragma unroll
    for (int i = 0; i < 4; ++i) {
        float pn = __shfl_xor(nrm[i], 32, 64);  // partner holds d±128
        float c = cosp[cbase + i];
        float s = sinp[cbase + i];
        out[i] = nrm[i] * c + sgn * pn * s;
    }

    uint2 o;
    o.x = (unsigned int)f2h(out[0]) | ((unsigned int)f2h(out[1]) << 16);
    o.y = (unsigned int)f2h(out[2]) | ((unsigned int)f2h(out[3]) << 16);
    *(uint2*)(ptr + d) = o;
}

// ---------------------------------------------------------------------------
// RMSNorm (weight = 1) of V, in place on V^T[KVD][TOKS]. Per (kvh, token):
// reduce over the 256-d column (stride TOKS), scale in place. Coalesced
// across the 256 threads (one token each).
// ---------------------------------------------------------------------------
__global__ __launch_bounds__(256) void vnorm_kernel(u16* __restrict__ Vt) {
    const int tok = blockIdx.x * 256 + threadIdx.x;  // 0..4095
    const int kvh = blockIdx.y;
    u16* p = Vt + (size_t)kvh * HD * TOKS + tok;
    float ss = 0.f;
#pragma unroll 4
    for (int d = 0; d < HD; ++d) {
        float v = h2f(p[(size_t)d * TOKS]);
        ss += v * v;
    }
    const float sc = rsqrtf(ss * (1.0f / 256.0f) + 1e-6f);
#pragma unroll 4
    for (int d = 0; d < HD; ++d) {
        const size_t idx = (size_t)d * TOKS;
        p[idx] = f2h(h2f(p[idx]) * sc);
    }
}

// ---------------------------------------------------------------------------
// MFMA flash attention, sliding window. Block = (q-tile of 64, h, b),
// 4 waves; wave owns 16 query rows, Q frags in registers. K tile staged
// LDS row-major [64][264]; V staged pre-transposed [256][72] (from Vt).
// Online softmax in D-fragment layout; P via per-wave LDS transpose.
// Fragment index conventions identical to gemm_bt (harness-verified).
// ---------------------------------------------------------------------------
#define QBLK 64
#define KVBLK 64

__global__ __launch_bounds__(256, 2) void attn_mfma(
        const u16* __restrict__ Q, const u16* __restrict__ K,
        const u16* __restrict__ Vt, u16* __restrict__ O) {
    __shared__ u16 Ks[64 * 264];      // 33792 B
    __shared__ u16 Vs[256 * 72];      // 36864 B
    __shared__ u16 Ps[4][16 * 72];    //  9216 B   (total 79872 B)

    const int tid = threadIdx.x;
    const int wave = tid >> 6, lane = tid & 63;
    const int quad = lane >> 4, l16 = lane & 15;
    const int q0 = blockIdx.x * QBLK;
    const int h = blockIdx.y, b = blockIdx.z;
    const int kvh = h >> 1;  // jnp.repeat(k, 2, axis=2)

    // Q fragments: A-operand row = l16, k = s*32 + quad*8
    half8 qf[8];
    {
        const u16* qp = Q + (size_t)(b * SEQ + q0 + wave * 16 + l16) * QD + h * HD + quad * 8;
#pragma unroll
        for (int s = 0; s < 8; ++s) qf[s] = *(const half8*)(qp + s * 32);
    }

    float mrow[4], lrow[4];
#pragma unroll
    for (int r = 0; r < 4; ++r) { mrow[r] = -1e30f; lrow[r] = 0.f; }
    floatx4 o[16];
#pragma unroll
    for (int n = 0; n < 16; ++n) o[n] = (floatx4){0.f, 0.f, 0.f, 0.f};

    int lo = q0 - (WINDOW - 1);
    const int t0 = (lo > 0 ? lo : 0) >> 6;
    const int tq = q0 >> 6;

    for (int t = t0; t <= tq; ++t) {
        const int k0 = t * KVBLK;
        __syncthreads();  // previous iteration's LDS reads complete
        {   // stage K tile: 64 rows x 256, rows of 512B per 32 lanes
            const int r = tid >> 5, c = (tid & 31) * 8;
            const u16* kp = K + (size_t)(b * SEQ + k0 + r) * KVD + kvh * HD + c;
#pragma unroll
            for (int p = 0; p < 8; ++p)
                *(short8*)(&Ks[(r + p * 8) * 264 + c]) = *(const short8*)(kp + (size_t)(p * 8) * KVD);
        }
        {   // stage V^T tile: 256 d-rows x 64 tokens
            const int r = tid >> 3, c = (tid & 7) * 8;
            const u16* vp = Vt + (size_t)(kvh * HD + r) * TOKS + b * SEQ + k0 + c;
#pragma unroll
            for (int p = 0; p < 8; ++p)
                *(short8*)(&Vs[(r + p * 32) * 72 + c]) = *(const short8*)(vp + (size_t)(p * 32) * TOKS);
        }
        __syncthreads();

        // QK^T: S[16q][64k], f32 accum
        floatx4 sf[4];
#pragma unroll
        for (int j = 0; j < 4; ++j) sf[j] = (floatx4){0.f, 0.f, 0.f, 0.f};
#pragma unroll
        for (int s = 0; s < 8; ++s) {
#pragma unroll
            for (int j = 0; j < 4; ++j) {
                half8 bf = *(const half8*)(&Ks[(j * 16 + l16) * 264 + s * 32 + quad * 8]);
                sf[j] = __builtin_amdgcn_mfma_f32_16x16x32_f16(qf[s], bf, sf[j], 0, 0, 0);
            }
        }

        // mask (diagonal tile and/or window-trailing-edge tile only)
        const bool needMask = (t == tq) || ((q0 + QBLK - 1) - k0 >= WINDOW);
        if (needMask) {
#pragma unroll
            for (int j = 0; j < 4; ++j) {
                const int kg = k0 + j * 16 + l16;
#pragma unroll
                for (int r = 0; r < 4; ++r) {
                    const int qg = q0 + wave * 16 + quad * 4 + r;
                    if (kg > qg || qg - kg >= WINDOW) sf[j][r] = -1e30f;
                }
            }
        }

        // online softmax; row r lives in the 16 lanes of this quad
#pragma unroll
        for (int r = 0; r < 4; ++r) {
            float mx = fmaxf(fmaxf(sf[0][r], sf[1][r]), fmaxf(sf[2][r], sf[3][r]));
            mx = fmaxf(mx, __shfl_xor(mx, 1, 64));
            mx = fmaxf(mx, __shfl_xor(mx, 2, 64));
            mx = fmaxf(mx, __shfl_xor(mx, 4, 64));
            mx = fmaxf(mx, __shfl_xor(mx, 8, 64));
            const float mnew = fmaxf(mrow[r], mx);
            const float rescale = __expf(mrow[r] - mnew);
            mrow[r] = mnew;
            float pv[4], ssum = 0.f;
#pragma unroll
            for (int j = 0; j < 4; ++j) {
                pv[j] = __expf(sf[j][r] - mnew);
                ssum += pv[j];
            }
            ssum += __shfl_xor(ssum, 1, 64);
            ssum += __shfl_xor(ssum, 2, 64);
            ssum += __shfl_xor(ssum, 4, 64);
            ssum += __shfl_xor(ssum, 8, 64);
            lrow[r] = lrow[r] * rescale + ssum;
#pragma unroll
            for (int n = 0; n < 16; ++n) o[n][r] *= rescale;
#pragma unroll
            for (int j = 0; j < 4; ++j)
                Ps[wave][(quad * 4 + r) * 72 + j * 16 + l16] = f2h(pv[j]);
        }

        // PV: O[16q][256d] += P[16q][64k] * V[64k][256d]
#pragma unroll
        for (int s2 = 0; s2 < 2; ++s2) {
            half8 pa = *(const half8*)(&Ps[wave][l16 * 72 + s2 * 32 + quad * 8]);
#pragma unroll
            for (int n = 0; n < 16; ++n) {
                half8 vb = *(const half8*)(&Vs[(n * 16 + l16) * 72 + s2 * 32 + quad * 8]);
                o[n] = __builtin_amdgcn_mfma_f32_16x16x32_f16(pa, vb, o[n], 0, 0, 0);
            }
        }
    }

    // epilogue: row = q0+wave*16+quad*4+r, col = h*HD + n*16 + l16
#pragma unroll
    for (int r = 0; r < 4; ++r) {
        const float inv = 1.0f / lrow[r];
        const size_t base = (size_t)(b * SEQ + q0 + wave * 16 + quad * 4 + r) * QD + h * HD + l16;
#pragma unroll
        for (int n = 0; n < 16; ++n)
            O[base + n * 16] = f2h(o[n][r] * inv);
    }
}

// ---------------------------------------------------------------------------
extern "C" void kernel_launch(void* const* d_in, const int* in_sizes, int n_in,
                              void* d_out, int out_size, void* d_ws, size_t ws_size,
                              hipStream_t stream) {
    const void*  X    = d_in[0];                 // hidden_states (2,2048,2816) f32
    const void*  Wq   = d_in[1];                 // (4096,2816) f32
    const void*  Wk   = d_in[2];                 // (2048,2816) f32
    const void*  Wv   = d_in[3];                 // (2048,2816) f32
    const void*  Wo   = d_in[4];                 // (2816,4096) f32
    const float* qw   = (const float*)d_in[5];   // (256,) f32
    const float* kw   = (const float*)d_in[6];   // (256,) f32
    const float* cosp = (const float*)d_in[7];   // (2,2048,256) f32
    const float* sinp = (const float*)d_in[8];   // (2,2048,256) f32

    char* ws = (char*)d_ws;
    u16* Qb = (u16*)(ws);                         // 4096x4096 f16 = 32 MB
    u16* Kb = (u16*)(ws + (size_t)33554432);      // 4096x2048 f16 = 16 MB
    u16* Vt = (u16*)(ws + (size_t)50331648);      // V^T: 2048x4096 f16 = 16 MB
    u16* Ob = (u16*)(ws + (size_t)67108864);      // 4096x4096 f16 = 32 MB

    const dim3 blk(256);
    gemm_bt<true, true, false, false><<<dim3(4096 / 128, 4096 / 128), blk, 0, stream>>>(X, Wq, Qb, 4096, 4096, 2816);
    gemm_bt<true, true, false, false><<<dim3(2048 / 128, 4096 / 128), blk, 0, stream>>>(X, Wk, Kb, 4096, 2048, 2816);
    gemm_bt<true, true, false, true ><<<dim3(2048 / 128, 4096 / 128), blk, 0, stream>>>(X, Wv, Vt, 4096, 2048, 2816);
    norm_rope_kernel<<<dim3((BATCH * SEQ * 32) / 4), blk, 0, stream>>>(Qb, Kb, qw, kw, cosp, sinp);
    vnorm_kernel<<<dim3(TOKS / 256, NKV), blk, 0, stream>>>(Vt);
    attn_mfma<<<dim3(SEQ / QBLK, NH, BATCH), blk, 0, stream>>>(Qb, Kb, Vt, Ob);
    gemm_bt<false, true, true, false><<<dim3(2816 / 128, 4096 / 128), blk, 0, stream>>>(Ob, Wo, d_out, 4096, 2816, 4096);
}

// Round 2
// 858.416 us; speedup vs baseline: 10.9524x; 1.1371x over previous
//
#include <hip/hip_runtime.h>
#include <math.h>

typedef unsigned short u16;
typedef __attribute__((ext_vector_type(8))) short short8;
typedef __attribute__((ext_vector_type(8))) _Float16 half8;
typedef __attribute__((ext_vector_type(4))) float floatx4;

#define NH 16
#define NKV 8
#define HD 256
#define SEQ 2048
#define BATCH 2
#define QD (NH * HD)    // 4096
#define KVD (NKV * HD)  // 2048
#define TOKS (BATCH * SEQ)  // 4096
#define WINDOW 1024

__device__ __forceinline__ u16 f2h(float f) {
    _Float16 h = (_Float16)f;
    return __builtin_bit_cast(u16, h);
}
__device__ __forceinline__ float h2f(u16 u) {
    return (float)__builtin_bit_cast(_Float16, u);
}

// async global->LDS, 16B per lane. lds ptr must be wave-uniform; HW deposits
// at lds + lane*16. global ptr is per-lane.
__device__ __forceinline__ void gload16(const u16* g, u16* l) {
    __builtin_amdgcn_global_load_lds(
        (const __attribute__((address_space(1))) unsigned int*)g,
        (__attribute__((address_space(3))) unsigned int*)l,
        16, 0, 0);
}

// ---------------------------------------------------------------------------
// f32 -> f16 conversion, 8 elem/thread, fully vectorized.
// ---------------------------------------------------------------------------
__global__ __launch_bounds__(256) void f32_to_f16(const float* __restrict__ in,
                                                  u16* __restrict__ out, int n8) {
    const int i = blockIdx.x * 256 + threadIdx.x;
    if (i >= n8) return;
    const float4 a = *((const float4*)in + 2 * (size_t)i);
    const float4 b = *((const float4*)in + 2 * (size_t)i + 1);
    short8 r;
    r[0] = (short)f2h(a.x); r[1] = (short)f2h(a.y);
    r[2] = (short)f2h(a.z); r[3] = (short)f2h(a.w);
    r[4] = (short)f2h(b.x); r[5] = (short)f2h(b.y);
    r[6] = (short)f2h(b.z); r[7] = (short)f2h(b.w);
    *((short8*)out + i) = r;
}

// ---------------------------------------------------------------------------
// GEMM (m97 structure): C[M,N] = A[M,K] * B[N,K]^T, f16 in, f32 accum.
// 128x128 tile, BK=32, 256 thr = 4 waves, each wave 64x64 (4x4 MFMA).
// Linear LDS [128][32] (fragment reads are a bijection onto contiguous 1KiB
// -> conflict-free); staged via global_load_lds dwordx4 (2 issues/wave per
// operand). OUTF32: f32 C. OUTT: store C transposed (u16) -> produces V^T.
// ---------------------------------------------------------------------------
template<bool OUTF32, bool OUTT>
__global__ __launch_bounds__(256) void gemm_lds(const u16* __restrict__ A,
                                                const u16* __restrict__ B,
                                                void* __restrict__ Cp,
                                                int M, int N, int K) {
    __shared__ u16 As[128 * 32];
    __shared__ u16 Bs[128 * 32];

    const int tid = threadIdx.x;
    const int wave = tid >> 6, lane = tid & 63;
    const int quad = lane >> 4, l16 = lane & 15;
    const int bm = blockIdx.y * 128, bn = blockIdx.x * 128;
    const int wm = (wave >> 1) * 64, wn = (wave & 1) * 64;

    // staging: wave w owns rows [w*32, w*32+32) of the tile; lane l supplies
    // row w*32 + l/4 (seg0) and +16 (seg1), cols (l&3)*8 .. +8.
    const int srow = wave * 32 + (lane >> 2);
    const int scol = (lane & 3) * 8;
    const u16* ga0 = A + (size_t)(bm + srow) * K + scol;
    const u16* ga1 = ga0 + (size_t)16 * K;
    const u16* gb0 = B + (size_t)(bn + srow) * K + scol;
    const u16* gb1 = gb0 + (size_t)16 * K;
    u16* lA0 = &As[wave * 1024];
    u16* lA1 = &As[wave * 1024 + 512];
    u16* lB0 = &Bs[wave * 1024];
    u16* lB1 = &Bs[wave * 1024 + 512];

    floatx4 acc[4][4];
#pragma unroll
    for (int i = 0; i < 4; ++i)
#pragma unroll
        for (int j = 0; j < 4; ++j) acc[i][j] = (floatx4){0.f, 0.f, 0.f, 0.f};

    const int kTiles = K >> 5;
    for (int kt = 0; kt < kTiles; ++kt) {
        __syncthreads();  // previous iteration's LDS reads complete
        gload16(ga0, lA0);
        gload16(ga1, lA1);
        gload16(gb0, lB0);
        gload16(gb1, lB1);
        ga0 += 32; ga1 += 32; gb0 += 32; gb1 += 32;
        __syncthreads();  // vmcnt(0) drain: tile resident

        half8 af[4], bfr[4];
#pragma unroll
        for (int i = 0; i < 4; ++i)
            af[i] = *(const half8*)(&As[(wm + i * 16 + l16) * 32 + quad * 8]);
#pragma unroll
        for (int j = 0; j < 4; ++j)
            bfr[j] = *(const half8*)(&Bs[(wn + j * 16 + l16) * 32 + quad * 8]);
#pragma unroll
        for (int i = 0; i < 4; ++i)
#pragma unroll
            for (int j = 0; j < 4; ++j)
                acc[i][j] = __builtin_amdgcn_mfma_f32_16x16x32_f16(af[i], bfr[j], acc[i][j], 0, 0, 0);
    }

    // epilogue: C row = bm+wm+i*16+quad*4+r, col = bn+wn+j*16+l16
#pragma unroll
    for (int i = 0; i < 4; ++i) {
#pragma unroll
        for (int j = 0; j < 4; ++j) {
            const int row0 = bm + wm + i * 16 + quad * 4;
            const int col = bn + wn + j * 16 + l16;
#pragma unroll
            for (int r = 0; r < 4; ++r) {
                if constexpr (OUTT)
                    ((u16*)Cp)[(size_t)col * M + row0 + r] = f2h(acc[i][j][r]);
                else if constexpr (OUTF32)
                    ((float*)Cp)[(size_t)(row0 + r) * N + col] = acc[i][j][r];
                else
                    ((u16*)Cp)[(size_t)(row0 + r) * N + col] = f2h(acc[i][j][r]);
            }
        }
    }
}

// ---------------------------------------------------------------------------
// Fused per-head RMSNorm (+weight) and RoPE for Q and K. One wave per
// (row, head-slot). slots: 0..15 Q heads, 16..23 K heads. In-place (f16).
// ---------------------------------------------------------------------------
__global__ __launch_bounds__(256) void norm_rope_kernel(
        u16* __restrict__ Q, u16* __restrict__ K,
        const float* __restrict__ qw, const float* __restrict__ kw,
        const float* __restrict__ cosp, const float* __restrict__ sinp) {
    const int w = blockIdx.x * 4 + (threadIdx.x >> 6);
    const int lane = threadIdx.x & 63;
    const int row = w >> 5;   // 0..4095 (= b*2048+s)
    const int sub = w & 31;
    if (sub >= 24) return;    // V handled by vnorm_kernel on V^T

    u16* ptr;
    const float* wt;
    if (sub < 16) { ptr = Q + (size_t)row * QD + sub * HD;         wt = qw; }
    else          { ptr = K + (size_t)row * KVD + (sub - 16) * HD; wt = kw; }

    const int d = lane * 4;
    uint2 raw = *(const uint2*)(ptr + d);
    float x[4];
    x[0] = h2f((u16)(raw.x & 0xffffu));
    x[1] = h2f((u16)(raw.x >> 16));
    x[2] = h2f((u16)(raw.y & 0xffffu));
    x[3] = h2f((u16)(raw.y >> 16));

    float ss = x[0] * x[0] + x[1] * x[1] + x[2] * x[2] + x[3] * x[3];
#pragma unroll
    for (int m = 1; m < 64; m <<= 1) ss += __shfl_xor(ss, m, 64);
    const float sc = rsqrtf(ss * (1.0f / 256.0f) + 1e-6f);

    float nrm[4];
#pragma unroll
    for (int i = 0; i < 4; ++i) nrm[i] = x[i] * sc * wt[d + i];

    const size_t cbase = (size_t)row * HD + d;
    const float sgn = (lane < 32) ? -1.0f : 1.0f;
    float out[4];
#pragma unroll
    for (int i = 0; i < 4; ++i) {
        float pn = __shfl_xor(nrm[i], 32, 64);  // partner holds d±128
        float c = cosp[cbase + i];
        float s = sinp[cbase + i];
        out[i] = nrm[i] * c + sgn * pn * s;
    }

    uint2 o;
    o.x = (unsigned int)f2h(out[0]) | ((unsigned int)f2h(out[1]) << 16);
    o.y = (unsigned int)f2h(out[2]) | ((unsigned int)f2h(out[3]) << 16);
    *(uint2*)(ptr + d) = o;
}

// ---------------------------------------------------------------------------
// RMSNorm (weight = 1) of V, in place on V^T[KVD][TOKS].
// ---------------------------------------------------------------------------
__global__ __launch_bounds__(256) void vnorm_kernel(u16* __restrict__ Vt) {
    const int tok = blockIdx.x * 256 + threadIdx.x;  // 0..4095
    const int kvh = blockIdx.y;
    u16* p = Vt + (size_t)kvh * HD * TOKS + tok;
    float ss = 0.f;
#pragma unroll 4
    for (int d = 0; d < HD; ++d) {
        float v = h2f(p[(size_t)d * TOKS]);
        ss += v * v;
    }
    const float sc = rsqrtf(ss * (1.0f / 256.0f) + 1e-6f);
#pragma unroll 4
    for (int d = 0; d < HD; ++d) {
        const size_t idx = (size_t)d * TOKS;
        p[idx] = f2h(h2f(p[idx]) * sc);
    }
}

// ---------------------------------------------------------------------------
// MFMA flash attention, sliding window. Block = (q-tile of 64, h, b),
// 4 waves; wave owns 16 query rows, Q frags in registers. K tile staged
// LDS row-major [64][264]; V staged pre-transposed [256][72] (from Vt).
// Online softmax in D-fragment layout; P via per-wave LDS transpose.
// ---------------------------------------------------------------------------
#define QBLK 64
#define KVBLK 64

__global__ __launch_bounds__(256, 2) void attn_mfma(
        const u16* __restrict__ Q, const u16* __restrict__ K,
        const u16* __restrict__ Vt, u16* __restrict__ O) {
    __shared__ u16 Ks[64 * 264];      // 33792 B
    __shared__ u16 Vs[256 * 72];      // 36864 B
    __shared__ u16 Ps[4][16 * 72];    //  9216 B   (total 79872 B)

    const int tid = threadIdx.x;
    const int wave = tid >> 6, lane = tid & 63;
    const int quad = lane >> 4, l16 = lane & 15;
    const int q0 = blockIdx.x * QBLK;
    const int h = blockIdx.y, b = blockIdx.z;
    const int kvh = h >> 1;  // jnp.repeat(k, 2, axis=2)

    // Q fragments: A-operand row = l16, k = s*32 + quad*8
    half8 qf[8];
    {
        const u16* qp = Q + (size_t)(b * SEQ + q0 + wave * 16 + l16) * QD + h * HD + quad * 8;
#pragma unroll
        for (int s = 0; s < 8; ++s) qf[s] = *(const half8*)(qp + s * 32);
    }

    float mrow[4], lrow[4];
#pragma unroll
    for (int r = 0; r < 4; ++r) { mrow[r] = -1e30f; lrow[r] = 0.f; }
    floatx4 o[16];
#pragma unroll
    for (int n = 0; n < 16; ++n) o[n] = (floatx4){0.f, 0.f, 0.f, 0.f};

    int lo = q0 - (WINDOW - 1);
    const int t0 = (lo > 0 ? lo : 0) >> 6;
    const int tq = q0 >> 6;

    for (int t = t0; t <= tq; ++t) {
        const int k0 = t * KVBLK;
        __syncthreads();  // previous iteration's LDS reads complete
        {   // stage K tile: 64 rows x 256
            const int r = tid >> 5, c = (tid & 31) * 8;
            const u16* kp = K + (size_t)(b * SEQ + k0 + r) * KVD + kvh * HD + c;
#pragma unroll
            for (int p = 0; p < 8; ++p)
                *(short8*)(&Ks[(r + p * 8) * 264 + c]) = *(const short8*)(kp + (size_t)(p * 8) * KVD);
        }
        {   // stage V^T tile: 256 d-rows x 64 tokens
            const int r = tid >> 3, c = (tid & 7) * 8;
            const u16* vp = Vt + (size_t)(kvh * HD + r) * TOKS + b * SEQ + k0 + c;
#pragma unroll
            for (int p = 0; p < 8; ++p)
                *(short8*)(&Vs[(r + p * 32) * 72 + c]) = *(const short8*)(vp + (size_t)(p * 32) * TOKS);
        }
        __syncthreads();

        // QK^T: S[16q][64k], f32 accum
        floatx4 sf[4];
#pragma unroll
        for (int j = 0; j < 4; ++j) sf[j] = (floatx4){0.f, 0.f, 0.f, 0.f};
#pragma unroll
        for (int s = 0; s < 8; ++s) {
#pragma unroll
            for (int j = 0; j < 4; ++j) {
                half8 bf = *(const half8*)(&Ks[(j * 16 + l16) * 264 + s * 32 + quad * 8]);
                sf[j] = __builtin_amdgcn_mfma_f32_16x16x32_f16(qf[s], bf, sf[j], 0, 0, 0);
            }
        }

        // mask (diagonal tile and/or window-trailing-edge tile only)
        const bool needMask = (t == tq) || ((q0 + QBLK - 1) - k0 >= WINDOW);
        if (needMask) {
#pragma unroll
            for (int j = 0; j < 4; ++j) {
                const int kg = k0 + j * 16 + l16;
#pragma unroll
                for (int r = 0; r < 4; ++r) {
                    const int qg = q0 + wave * 16 + quad * 4 + r;
                    if (kg > qg || qg - kg >= WINDOW) sf[j][r] = -1e30f;
                }
            }
        }

        // online softmax; row r lives in the 16 lanes of this quad
#pragma unroll
        for (int r = 0; r < 4; ++r) {
            float mx = fmaxf(fmaxf(sf[0][r], sf[1][r]), fmaxf(sf[2][r], sf[3][r]));
            mx = fmaxf(mx, __shfl_xor(mx, 1, 64));
            mx = fmaxf(mx, __shfl_xor(mx, 2, 64));
            mx = fmaxf(mx, __shfl_xor(mx, 4, 64));
            mx = fmaxf(mx, __shfl_xor(mx, 8, 64));
            const float mnew = fmaxf(mrow[r], mx);
            const float rescale = __expf(mrow[r] - mnew);
            mrow[r] = mnew;
            float pv[4], ssum = 0.f;
#pragma unroll
            for (int j = 0; j < 4; ++j) {
                pv[j] = __expf(sf[j][r] - mnew);
                ssum += pv[j];
            }
            ssum += __shfl_xor(ssum, 1, 64);
            ssum += __shfl_xor(ssum, 2, 64);
            ssum += __shfl_xor(ssum, 4, 64);
            ssum += __shfl_xor(ssum, 8, 64);
            lrow[r] = lrow[r] * rescale + ssum;
#pragma unroll
            for (int n = 0; n < 16; ++n) o[n][r] *= rescale;
#pragma unroll
            for (int j = 0; j < 4; ++j)
                Ps[wave][(quad * 4 + r) * 72 + j * 16 + l16] = f2h(pv[j]);
        }

        // PV: O[16q][256d] += P[16q][64k] * V[64k][256d]
#pragma unroll
        for (int s2 = 0; s2 < 2; ++s2) {
            half8 pa = *(const half8*)(&Ps[wave][l16 * 72 + s2 * 32 + quad * 8]);
#pragma unroll
            for (int n = 0; n < 16; ++n) {
                half8 vb = *(const half8*)(&Vs[(n * 16 + l16) * 72 + s2 * 32 + quad * 8]);
                o[n] = __builtin_amdgcn_mfma_f32_16x16x32_f16(pa, vb, o[n], 0, 0, 0);
            }
        }
    }

    // epilogue: row = q0+wave*16+quad*4+r, col = h*HD + n*16 + l16
#pragma unroll
    for (int r = 0; r < 4; ++r) {
        const float inv = 1.0f / lrow[r];
        const size_t base = (size_t)(b * SEQ + q0 + wave * 16 + quad * 4 + r) * QD + h * HD + l16;
#pragma unroll
        for (int n = 0; n < 16; ++n)
            O[base + n * 16] = f2h(o[n][r] * inv);
    }
}

// ---------------------------------------------------------------------------
// Workspace / scratch plan (ws proven >= 100.6 MB by previous rounds):
//   ws[ 0, 32M)  Qb (gemmQ..attn), then Woh f16 23M (convert after attn)
//   ws[32, 48M)  Kb
//   ws[48, 64M)  Vt
//   ws[64, 96M)  Ob (attn..gemmO); before attn this region holds Wkh/Wvh
//   d_out (46.1 MB f32, written only by final gemm): holds Xh (23.07M) +
//   Wqh (23.07M) exactly; both dead before gemmO writes d_out.
// ---------------------------------------------------------------------------
extern "C" void kernel_launch(void* const* d_in, const int* in_sizes, int n_in,
                              void* d_out, int out_size, void* d_ws, size_t ws_size,
                              hipStream_t stream) {
    const float* X    = (const float*)d_in[0];   // (2,2048,2816) f32
    const float* Wq   = (const float*)d_in[1];   // (4096,2816) f32
    const float* Wk   = (const float*)d_in[2];   // (2048,2816) f32
    const float* Wv   = (const float*)d_in[3];   // (2048,2816) f32
    const float* Wo   = (const float*)d_in[4];   // (2816,4096) f32
    const float* qw   = (const float*)d_in[5];   // (256,) f32
    const float* kw   = (const float*)d_in[6];   // (256,) f32
    const float* cosp = (const float*)d_in[7];   // (2,2048,256) f32
    const float* sinp = (const float*)d_in[8];   // (2,2048,256) f32

    char* ws = (char*)d_ws;
    u16* Qb  = (u16*)(ws);                        // 32 MB
    u16* Kb  = (u16*)(ws + (size_t)33554432);     // 16 MB
    u16* Vt  = (u16*)(ws + (size_t)50331648);     // V^T 16 MB
    u16* Ob  = (u16*)(ws + (size_t)67108864);     // 32 MB (attn output)
    u16* Wkh = (u16*)(ws + (size_t)67108864);     // 11.5 MB, dead before attn
    u16* Wvh = (u16*)(ws + (size_t)78643200);     // 11.5 MB, dead before attn
    u16* Woh = (u16*)(ws);                        // 23 MB, after attn (Qb dead)

    u16* Xh  = (u16*)d_out;                       // 23.07 MB
    u16* Wqh = (u16*)d_out + (size_t)11534336;    // 23.07 MB (ends exactly at out_size)

    const dim3 blk(256);
    // conversions: n/8 elems per thread-8; all sizes divide 2048*8
    f32_to_f16<<<dim3(5632), blk, 0, stream>>>(X,  Xh,  11534336 / 8);
    f32_to_f16<<<dim3(5632), blk, 0, stream>>>(Wq, Wqh, 11534336 / 8);
    gemm_lds<false, false><<<dim3(4096 / 128, 4096 / 128), blk, 0, stream>>>(Xh, Wqh, Qb, 4096, 4096, 2816);
    f32_to_f16<<<dim3(2816), blk, 0, stream>>>(Wk, Wkh, 5767168 / 8);
    gemm_lds<false, false><<<dim3(2048 / 128, 4096 / 128), blk, 0, stream>>>(Xh, Wkh, Kb, 4096, 2048, 2816);
    f32_to_f16<<<dim3(2816), blk, 0, stream>>>(Wv, Wvh, 5767168 / 8);
    gemm_lds<false, true ><<<dim3(2048 / 128, 4096 / 128), blk, 0, stream>>>(Xh, Wvh, Vt, 4096, 2048, 2816);
    norm_rope_kernel<<<dim3((BATCH * SEQ * 32) / 4), blk, 0, stream>>>(Qb, Kb, qw, kw, cosp, sinp);
    vnorm_kernel<<<dim3(TOKS / 256, NKV), blk, 0, stream>>>(Vt);
    attn_mfma<<<dim3(SEQ / QBLK, NH, BATCH), blk, 0, stream>>>(Qb, Kb, Vt, Ob);
    f32_to_f16<<<dim3(5632), blk, 0, stream>>>(Wo, Woh, 11534336 / 8);
    gemm_lds<true, false><<<dim3(2816 / 128, 4096 / 128), blk, 0, stream>>>(Ob, Woh, d_out, 4096, 2816, 4096);
}

// Round 3
// 833.341 us; speedup vs baseline: 11.2819x; 1.0301x over previous
//
#include <hip/hip_runtime.h>
#include <math.h>

typedef unsigned short u16;
typedef __attribute__((ext_vector_type(8))) short short8;
typedef __attribute__((ext_vector_type(8))) _Float16 half8;
typedef __attribute__((ext_vector_type(4))) float floatx4;

#define NH 16
#define NKV 8
#define HD 256
#define SEQ 2048
#define BATCH 2
#define QD (NH * HD)    // 4096
#define KVD (NKV * HD)  // 2048
#define TOKS (BATCH * SEQ)  // 4096
#define WINDOW 1024

__device__ __forceinline__ u16 f2h(float f) {
    _Float16 h = (_Float16)f;
    return __builtin_bit_cast(u16, h);
}
__device__ __forceinline__ float h2f(u16 u) {
    return (float)__builtin_bit_cast(_Float16, u);
}

// async global->LDS, 16B per lane. lds ptr is wave-uniform; HW deposits at
// lds + lane*16. global ptr is per-lane (enables pre-swizzled sources).
__device__ __forceinline__ void gload16(const u16* g, u16* l) {
    __builtin_amdgcn_global_load_lds(
        (const __attribute__((address_space(1))) unsigned int*)g,
        (__attribute__((address_space(3))) unsigned int*)l,
        16, 0, 0);
}

// ---------------------------------------------------------------------------
// f32 -> f16 conversion, 8 elem/thread, fully vectorized.
// ---------------------------------------------------------------------------
__global__ __launch_bounds__(256) void f32_to_f16(const float* __restrict__ in,
                                                  u16* __restrict__ out, int n8) {
    const int i = blockIdx.x * 256 + threadIdx.x;
    if (i >= n8) return;
    const float4 a = *((const float4*)in + 2 * (size_t)i);
    const float4 b = *((const float4*)in + 2 * (size_t)i + 1);
    short8 r;
    r[0] = (short)f2h(a.x); r[1] = (short)f2h(a.y);
    r[2] = (short)f2h(a.z); r[3] = (short)f2h(a.w);
    r[4] = (short)f2h(b.x); r[5] = (short)f2h(b.y);
    r[6] = (short)f2h(b.z); r[7] = (short)f2h(b.w);
    *((short8*)out + i) = r;
}

// ---------------------------------------------------------------------------
// Shared GEMM core (m97 structure): 128x128 tile, BK=32, 4 waves, f16 MFMA,
// linear LDS staged via global_load_lds dwordx4.
// ---------------------------------------------------------------------------
#define GEMM_PRE()                                                            \
    __shared__ u16 As[128 * 32];                                              \
    __shared__ u16 Bs[128 * 32];                                              \
    const int tid = threadIdx.x;                                              \
    const int wave = tid >> 6, lane = tid & 63;                               \
    const int quad = lane >> 4, l16 = lane & 15;                              \
    const int bm = blockIdx.y * 128, bn = blockIdx.x * 128;                   \
    const int wm = (wave >> 1) * 64, wn = (wave & 1) * 64;                    \
    const int srow = wave * 32 + (lane >> 2);                                 \
    const int scol = (lane & 3) * 8;                                          \
    const u16* ga0 = A + (size_t)(bm + srow) * K + scol;                      \
    const u16* ga1 = ga0 + (size_t)16 * K;                                    \
    const u16* gb0 = B + (size_t)(bn + srow) * K + scol;                      \
    const u16* gb1 = gb0 + (size_t)16 * K;                                    \
    u16* lA0 = &As[wave * 1024];                                              \
    u16* lA1 = &As[wave * 1024 + 512];                                        \
    u16* lB0 = &Bs[wave * 1024];                                              \
    u16* lB1 = &Bs[wave * 1024 + 512];                                        \
    floatx4 acc[4][4];                                                        \
    _Pragma("unroll")                                                         \
    for (int i = 0; i < 4; ++i)                                               \
        _Pragma("unroll")                                                     \
        for (int j = 0; j < 4; ++j) acc[i][j] = (floatx4){0.f, 0.f, 0.f, 0.f};\
    const int kTiles = K >> 5;                                                \
    for (int kt = 0; kt < kTiles; ++kt) {                                     \
        __syncthreads();                                                      \
        gload16(ga0, lA0);                                                    \
        gload16(ga1, lA1);                                                    \
        gload16(gb0, lB0);                                                    \
        gload16(gb1, lB1);                                                    \
        ga0 += 32; ga1 += 32; gb0 += 32; gb1 += 32;                           \
        __syncthreads();                                                      \
        half8 af[4], bfr[4];                                                  \
        _Pragma("unroll")                                                     \
        for (int i = 0; i < 4; ++i)                                           \
            af[i] = *(const half8*)(&As[(wm + i * 16 + l16) * 32 + quad * 8]);\
        _Pragma("unroll")                                                     \
        for (int j = 0; j < 4; ++j)                                           \
            bfr[j] = *(const half8*)(&Bs[(wn + j * 16 + l16) * 32 + quad * 8]);\
        _Pragma("unroll")                                                     \
        for (int i = 0; i < 4; ++i)                                           \
            _Pragma("unroll")                                                 \
            for (int j = 0; j < 4; ++j)                                       \
                acc[i][j] = __builtin_amdgcn_mfma_f32_16x16x32_f16(af[i], bfr[j], acc[i][j], 0, 0, 0); \
    }

// ---------------------------------------------------------------------------
// Generic GEMM: C[M,N] = A[M,K]*B[N,K]^T. OUTF32 selects f32 output.
// ---------------------------------------------------------------------------
template<bool OUTF32>
__global__ __launch_bounds__(256) void gemm_lds(const u16* __restrict__ A,
                                                const u16* __restrict__ B,
                                                void* __restrict__ Cp,
                                                int M, int N, int K) {
    GEMM_PRE()
#pragma unroll
    for (int i = 0; i < 4; ++i) {
#pragma unroll
        for (int j = 0; j < 4; ++j) {
            const int row0 = bm + wm + i * 16 + quad * 4;
            const int col = bn + wn + j * 16 + l16;
#pragma unroll
            for (int r = 0; r < 4; ++r) {
                if constexpr (OUTF32)
                    ((float*)Cp)[(size_t)(row0 + r) * N + col] = acc[i][j][r];
                else
                    ((u16*)Cp)[(size_t)(row0 + r) * N + col] = f2h(acc[i][j][r]);
            }
        }
    }
}

// ---------------------------------------------------------------------------
// Fused QKV GEMM: A = Xh[4096][2816], B = Wqkv[8192][2816] (rows 0..4095 Wq,
// 4096..6143 Wk, 6144..8191 Wv). N = 8192. Epilogue routes per region
// (block-uniform: boundaries are multiples of 128); V region is stored
// transposed -> produces V^T[2048][4096] directly.
// ---------------------------------------------------------------------------
__global__ __launch_bounds__(256) void gemm_qkv(const u16* __restrict__ A,
                                                const u16* __restrict__ B,
                                                u16* __restrict__ Qb,
                                                u16* __restrict__ Kb,
                                                u16* __restrict__ Vt,
                                                int M, int N, int K) {
    GEMM_PRE()
#pragma unroll
    for (int i = 0; i < 4; ++i) {
#pragma unroll
        for (int j = 0; j < 4; ++j) {
            const int row0 = bm + wm + i * 16 + quad * 4;
            const int col = bn + wn + j * 16 + l16;
#pragma unroll
            for (int r = 0; r < 4; ++r) {
                const u16 hv = f2h(acc[i][j][r]);
                if (bn < 4096)
                    Qb[(size_t)(row0 + r) * QD + col] = hv;
                else if (bn < 6144)
                    Kb[(size_t)(row0 + r) * KVD + (col - 4096)] = hv;
                else
                    Vt[(size_t)(col - 6144) * TOKS + row0 + r] = hv;
            }
        }
    }
}

// ---------------------------------------------------------------------------
// Fused per-head RMSNorm (+weight) and RoPE for Q and K. One wave per
// (row, head-slot). slots: 0..15 Q heads, 16..23 K heads. In-place (f16).
// ---------------------------------------------------------------------------
__global__ __launch_bounds__(256) void norm_rope_kernel(
        u16* __restrict__ Q, u16* __restrict__ K,
        const float* __restrict__ qw, const float* __restrict__ kw,
        const float* __restrict__ cosp, const float* __restrict__ sinp) {
    const int w = blockIdx.x * 4 + (threadIdx.x >> 6);
    const int lane = threadIdx.x & 63;
    const int row = w >> 5;   // 0..4095 (= b*2048+s)
    const int sub = w & 31;
    if (sub >= 24) return;    // V handled by vnorm_kernel on V^T

    u16* ptr;
    const float* wt;
    if (sub < 16) { ptr = Q + (size_t)row * QD + sub * HD;         wt = qw; }
    else          { ptr = K + (size_t)row * KVD + (sub - 16) * HD; wt = kw; }

    const int d = lane * 4;
    uint2 raw = *(const uint2*)(ptr + d);
    float x[4];
    x[0] = h2f((u16)(raw.x & 0xffffu));
    x[1] = h2f((u16)(raw.x >> 16));
    x[2] = h2f((u16)(raw.y & 0xffffu));
    x[3] = h2f((u16)(raw.y >> 16));

    float ss = x[0] * x[0] + x[1] * x[1] + x[2] * x[2] + x[3] * x[3];
#pragma unroll
    for (int m = 1; m < 64; m <<= 1) ss += __shfl_xor(ss, m, 64);
    const float sc = rsqrtf(ss * (1.0f / 256.0f) + 1e-6f);

    float nrm[4];
#pragma unroll
    for (int i = 0; i < 4; ++i) nrm[i] = x[i] * sc * wt[d + i];

    const size_t cbase = (size_t)row * HD + d;
    const float sgn = (lane < 32) ? -1.0f : 1.0f;
    float out[4];
#pragma unroll
    for (int i = 0; i < 4; ++i) {
        float pn = __shfl_xor(nrm[i], 32, 64);  // partner holds d±128
        float c = cosp[cbase + i];
        float s = sinp[cbase + i];
        out[i] = nrm[i] * c + sgn * pn * s;
    }

    uint2 o;
    o.x = (unsigned int)f2h(out[0]) | ((unsigned int)f2h(out[1]) << 16);
    o.y = (unsigned int)f2h(out[2]) | ((unsigned int)f2h(out[3]) << 16);
    *(uint2*)(ptr + d) = o;
}

// ---------------------------------------------------------------------------
// RMSNorm (weight = 1) of V, in place on V^T[KVD][TOKS].
// ---------------------------------------------------------------------------
__global__ __launch_bounds__(256) void vnorm_kernel(u16* __restrict__ Vt) {
    const int tok = blockIdx.x * 256 + threadIdx.x;  // 0..4095
    const int kvh = blockIdx.y;
    u16* p = Vt + (size_t)kvh * HD * TOKS + tok;
    float ss = 0.f;
#pragma unroll 4
    for (int d = 0; d < HD; ++d) {
        float v = h2f(p[(size_t)d * TOKS]);
        ss += v * v;
    }
    const float sc = rsqrtf(ss * (1.0f / 256.0f) + 1e-6f);
#pragma unroll 4
    for (int d = 0; d < HD; ++d) {
        const size_t idx = (size_t)d * TOKS;
        p[idx] = f2h(h2f(p[idx]) * sc);
    }
}

// ---------------------------------------------------------------------------
// MFMA flash attention, sliding window. Block = (q-tile of 64, h, b),
// 4 waves; wave owns 16 query rows, Q frags in registers.
// K/V staged via global_load_lds (async, no VGPR round-trip) into LINEAR
// LDS tiles; the row-major 32-way bank hazard is fixed by XOR-swizzle
// byte ^= ((row&7)<<4), applied BOTH on the per-lane global source address
// (pre-swizzle, since gload_lds deposits linearly) and on the ds_read
// fragment address (rule #21: both-sides-or-neither).
// ---------------------------------------------------------------------------
#define QBLK 64
#define KVBLK 64

__global__ __launch_bounds__(256, 2) void attn_mfma(
        const u16* __restrict__ Q, const u16* __restrict__ K,
        const u16* __restrict__ Vt, u16* __restrict__ O) {
    __shared__ u16 Ks[64 * 256];      // 32768 B, row = key token, 512B/row
    __shared__ u16 Vs[256 * 64];      // 32768 B, row = dim d, 128B/row
    __shared__ u16 Ps[4][16 * 72];    //  9216 B  (total 74752 B -> 2 blk/CU)

    const int tid = threadIdx.x;
    const int wave = tid >> 6, lane = tid & 63;
    const int quad = lane >> 4, l16 = lane & 15;
    const int q0 = blockIdx.x * QBLK;
    const int h = blockIdx.y, b = blockIdx.z;
    const int kvh = h >> 1;  // jnp.repeat(k, 2, axis=2)

    // Q fragments: A-operand row = l16, k = s*32 + quad*8
    half8 qf[8];
    {
        const u16* qp = Q + (size_t)(b * SEQ + q0 + wave * 16 + l16) * QD + h * HD + quad * 8;
#pragma unroll
        for (int s = 0; s < 8; ++s) qf[s] = *(const half8*)(qp + s * 32);
    }

    float mrow[4], lrow[4];
#pragma unroll
    for (int r = 0; r < 4; ++r) { mrow[r] = -1e30f; lrow[r] = 0.f; }
    floatx4 o[16];
#pragma unroll
    for (int n = 0; n < 16; ++n) o[n] = (floatx4){0.f, 0.f, 0.f, 0.f};

    int lo = q0 - (WINDOW - 1);
    const int t0 = (lo > 0 ? lo : 0) >> 6;
    const int tq = q0 >> 6;

    // per-lane staging constants
    const int kr2 = wave * 2 + (lane >> 5);        // K: row within 2-row group
    const int kcb = (lane & 31) * 16;              // K: stored col byte
    const int vr8 = wave * 8 + (lane >> 3);        // V: row within 8-row group
    const int vcb = (lane & 7) * 16;               // V: stored col byte

    for (int t = t0; t <= tq; ++t) {
        const int k0 = t * KVBLK;
        __syncthreads();  // previous iteration's LDS reads complete
        // async stage K tile [64 tok][256 d], pre-swizzled source
#pragma unroll
        for (int p = 0; p < 8; ++p) {
            const int row = p * 8 + kr2;
            const int scb = kcb ^ ((row & 7) << 4);
            const u16* g = K + (size_t)(b * SEQ + k0 + row) * KVD + kvh * HD + (scb >> 1);
            gload16(g, &Ks[p * 2048 + wave * 512]);
        }
        // async stage V^T tile [256 d][64 tok], pre-swizzled source
#pragma unroll
        for (int p = 0; p < 8; ++p) {
            const int row = p * 32 + vr8;
            const int scb = vcb ^ ((row & 7) << 4);
            const u16* g = Vt + (size_t)(kvh * HD + row) * TOKS + b * SEQ + k0 + (scb >> 1);
            gload16(g, &Vs[p * 2048 + wave * 512]);
        }
        __syncthreads();  // vmcnt(0) drain: both tiles resident

        // QK^T: S[16q][64k], f32 accum
        floatx4 sf[4];
#pragma unroll
        for (int j = 0; j < 4; ++j) sf[j] = (floatx4){0.f, 0.f, 0.f, 0.f};
        __builtin_amdgcn_s_setprio(1);
#pragma unroll
        for (int s = 0; s < 8; ++s) {
#pragma unroll
            for (int j = 0; j < 4; ++j) {
                half8 bf = *(const half8*)(&Ks[(j * 16 + l16) * 256 +
                                               ((s * 32 + quad * 8) ^ ((l16 & 7) << 3))]);
                sf[j] = __builtin_amdgcn_mfma_f32_16x16x32_f16(qf[s], bf, sf[j], 0, 0, 0);
            }
        }
        __builtin_amdgcn_s_setprio(0);

        // mask (diagonal tile and/or window-trailing-edge tile only)
        const bool needMask = (t == tq) || ((q0 + QBLK - 1) - k0 >= WINDOW);
        if (needMask) {
#pragma unroll
            for (int j = 0; j < 4; ++j) {
                const int kg = k0 + j * 16 + l16;
#pragma unroll
                for (int r = 0; r < 4; ++r) {
                    const int qg = q0 + wave * 16 + quad * 4 + r;
                    if (kg > qg || qg - kg >= WINDOW) sf[j][r] = -1e30f;
                }
            }
        }

        // online softmax; row r lives in the 16 lanes of this quad
#pragma unroll
        for (int r = 0; r < 4; ++r) {
            float mx = fmaxf(fmaxf(sf[0][r], sf[1][r]), fmaxf(sf[2][r], sf[3][r]));
            mx = fmaxf(mx, __shfl_xor(mx, 1, 64));
            mx = fmaxf(mx, __shfl_xor(mx, 2, 64));
            mx = fmaxf(mx, __shfl_xor(mx, 4, 64));
            mx = fmaxf(mx, __shfl_xor(mx, 8, 64));
            const float mnew = fmaxf(mrow[r], mx);
            const float rescale = __expf(mrow[r] - mnew);
            mrow[r] = mnew;
            float pv[4], ssum = 0.f;
#pragma unroll
            for (int j = 0; j < 4; ++j) {
                pv[j] = __expf(sf[j][r] - mnew);
                ssum += pv[j];
            }
            ssum += __shfl_xor(ssum, 1, 64);
            ssum += __shfl_xor(ssum, 2, 64);
            ssum += __shfl_xor(ssum, 4, 64);
            ssum += __shfl_xor(ssum, 8, 64);
            lrow[r] = lrow[r] * rescale + ssum;
#pragma unroll
            for (int n = 0; n < 16; ++n) o[n][r] *= rescale;
#pragma unroll
            for (int j = 0; j < 4; ++j)
                Ps[wave][(quad * 4 + r) * 72 + j * 16 + l16] = f2h(pv[j]);
        }

        // PV: O[16q][256d] += P[16q][64k] * V[64k][256d]
        __builtin_amdgcn_s_setprio(1);
#pragma unroll
        for (int s2 = 0; s2 < 2; ++s2) {
            half8 pa = *(const half8*)(&Ps[wave][l16 * 72 + s2 * 32 + quad * 8]);
#pragma unroll
            for (int n = 0; n < 16; ++n) {
                half8 vb = *(const half8*)(&Vs[(n * 16 + l16) * 64 +
                                               ((s2 * 32 + quad * 8) ^ ((l16 & 7) << 3))]);
                o[n] = __builtin_amdgcn_mfma_f32_16x16x32_f16(pa, vb, o[n], 0, 0, 0);
            }
        }
        __builtin_amdgcn_s_setprio(0);
    }

    // epilogue: row = q0+wave*16+quad*4+r, col = h*HD + n*16 + l16
#pragma unroll
    for (int r = 0; r < 4; ++r) {
        const float inv = 1.0f / lrow[r];
        const size_t base = (size_t)(b * SEQ + q0 + wave * 16 + quad * 4 + r) * QD + h * HD + l16;
#pragma unroll
        for (int n = 0; n < 16; ++n)
            O[base + n * 16] = f2h(o[n][r] * inv);
    }
}

// ---------------------------------------------------------------------------
// Workspace plan (ws proven >= 100,663,296 B by previous rounds):
//   ws[ 0,32M)  Qb (qkv gemm..attn); then Woh f16 23.07M (after attn)
//   ws[32,48M)  Kb
//   ws[48,64M)  Vt (V^T [2048][4096])
//   ws[64,96M)  Xh f16 23.07M (dead after qkv gemm) -> then Ob (attn out)
//   d_out (46,137,344 B): Wqkv f16 [8192][2816] = exactly out_size; dead
//   before the final gemm overwrites d_out.
// ---------------------------------------------------------------------------
extern "C" void kernel_launch(void* const* d_in, const int* in_sizes, int n_in,
                              void* d_out, int out_size, void* d_ws, size_t ws_size,
                              hipStream_t stream) {
    const float* X    = (const float*)d_in[0];   // (2,2048,2816) f32
    const float* Wq   = (const float*)d_in[1];   // (4096,2816) f32
    const float* Wk   = (const float*)d_in[2];   // (2048,2816) f32
    const float* Wv   = (const float*)d_in[3];   // (2048,2816) f32
    const float* Wo   = (const float*)d_in[4];   // (2816,4096) f32
    const float* qw   = (const float*)d_in[5];   // (256,) f32
    const float* kw   = (const float*)d_in[6];   // (256,) f32
    const float* cosp = (const float*)d_in[7];   // (2,2048,256) f32
    const float* sinp = (const float*)d_in[8];   // (2,2048,256) f32

    char* ws = (char*)d_ws;
    u16* Qb  = (u16*)(ws);                        // 32 MB
    u16* Kb  = (u16*)(ws + (size_t)33554432);     // 16 MB
    u16* Vt  = (u16*)(ws + (size_t)50331648);     // V^T 16 MB
    u16* Xh  = (u16*)(ws + (size_t)67108864);     // 23.07 MB, dead after qkv
    u16* Ob  = (u16*)(ws + (size_t)67108864);     // 32 MB (attn output)
    u16* Woh = (u16*)(ws);                        // 23.07 MB, after attn

    u16* Wqkv = (u16*)d_out;                      // [8192][2816] f16 = 46.14 MB

    const dim3 blk(256);
    f32_to_f16<<<dim3(5632), blk, 0, stream>>>(X,  Xh, 11534336 / 8);
    f32_to_f16<<<dim3(5632), blk, 0, stream>>>(Wq, Wqkv, 11534336 / 8);
    f32_to_f16<<<dim3(2816), blk, 0, stream>>>(Wk, Wqkv + (size_t)4096 * 2816, 5767168 / 8);
    f32_to_f16<<<dim3(2816), blk, 0, stream>>>(Wv, Wqkv + (size_t)6144 * 2816, 5767168 / 8);
    gemm_qkv<<<dim3(8192 / 128, 4096 / 128), blk, 0, stream>>>(Xh, Wqkv, Qb, Kb, Vt, 4096, 8192, 2816);
    norm_rope_kernel<<<dim3((BATCH * SEQ * 32) / 4), blk, 0, stream>>>(Qb, Kb, qw, kw, cosp, sinp);
    vnorm_kernel<<<dim3(TOKS / 256, NKV), blk, 0, stream>>>(Vt);
    attn_mfma<<<dim3(SEQ / QBLK, NH, BATCH), blk, 0, stream>>>(Qb, Kb, Vt, Ob);
    f32_to_f16<<<dim3(5632), blk, 0, stream>>>(Wo, Woh, 11534336 / 8);
    gemm_lds<true><<<dim3(2816 / 128, 4096 / 128), blk, 0, stream>>>(Ob, Woh, d_out, 4096, 2816, 4096);
}

// Round 4
// 778.915 us; speedup vs baseline: 12.0702x; 1.0699x over previous
//
#include <hip/hip_runtime.h>
#include <math.h>

typedef unsigned short u16;
typedef __attribute__((ext_vector_type(8))) short short8;
typedef __attribute__((ext_vector_type(8))) _Float16 half8;
typedef __attribute__((ext_vector_type(4))) float floatx4;

#define NH 16
#define NKV 8
#define HD 256
#define SEQ 2048
#define BATCH 2
#define QD (NH * HD)    // 4096
#define KVD (NKV * HD)  // 2048
#define TOKS (BATCH * SEQ)  // 4096
#define WINDOW 1024

__device__ __forceinline__ u16 f2h(float f) {
    _Float16 h = (_Float16)f;
    return __builtin_bit_cast(u16, h);
}
__device__ __forceinline__ float h2f(u16 u) {
    return (float)__builtin_bit_cast(_Float16, u);
}

// async global->LDS, 16B per lane. lds ptr is wave-uniform; HW deposits at
// lds + lane*16. global ptr is per-lane (enables pre-swizzled sources).
__device__ __forceinline__ void gload16(const u16* g, u16* l) {
    __builtin_amdgcn_global_load_lds(
        (const __attribute__((address_space(1))) unsigned int*)g,
        (__attribute__((address_space(3))) unsigned int*)l,
        16, 0, 0);
}

// ---------------------------------------------------------------------------
// f32 -> f16 conversion, 8 elem/thread, fully vectorized.
// ---------------------------------------------------------------------------
__global__ __launch_bounds__(256) void f32_to_f16(const float* __restrict__ in,
                                                  u16* __restrict__ out, int n8) {
    const int i = blockIdx.x * 256 + threadIdx.x;
    if (i >= n8) return;
    const float4 a = *((const float4*)in + 2 * (size_t)i);
    const float4 b = *((const float4*)in + 2 * (size_t)i + 1);
    short8 r;
    r[0] = (short)f2h(a.x); r[1] = (short)f2h(a.y);
    r[2] = (short)f2h(a.z); r[3] = (short)f2h(a.w);
    r[4] = (short)f2h(b.x); r[5] = (short)f2h(b.y);
    r[6] = (short)f2h(b.z); r[7] = (short)f2h(b.w);
    *((short8*)out + i) = r;
}

// ---------------------------------------------------------------------------
// 256x256xBK64 double-buffered QKV GEMM (T3-minimal 2-phase, counted vmcnt).
// A = Xh[4096][2816], B = Wqkv[8192][2816] (rows 0..4095 Wq, 4096..6143 Wk,
// 6144..8191 Wv). 512 threads = 8 waves (2M x 4N), per-wave 128x64 output.
// LDS 128 KB: As/Bs [2 buf][256 rows][64 k] u16, XOR-swizzled
// (byte ^= ((row&7)<<4)) on BOTH sides: pre-swizzled global source for the
// linear global_load_lds deposit, and swizzled ds_read fragment address.
// Sync per iteration: STAGE(t+1) -> vmcnt(8) [tile t resident, t+1 in
// flight] -> s_barrier -> compute -> s_barrier. Never vmcnt(0) mid-loop.
// ---------------------------------------------------------------------------
#define QKV_K 2816
#define QKV_NT (QKV_K / 64)   // 44

__global__ __launch_bounds__(512, 2) void gemm256_qkv(
        const u16* __restrict__ A, const u16* __restrict__ B,
        u16* __restrict__ Qb, u16* __restrict__ Kb, u16* __restrict__ Vt) {
    __shared__ u16 As[2 * 16384];   // 64 KB
    __shared__ u16 Bs[2 * 16384];   // 64 KB

    const int tid = threadIdx.x;
    const int wave = tid >> 6, lane = tid & 63;
    const int quad = lane >> 4, l16 = lane & 15;
    const int wr = wave >> 2, wc = wave & 3;

    // XCD-bijective swizzle: nwg = 512 (32 bn x 16 bm), q = 64
    const int wg0 = (int)blockIdx.x;
    const int wg = (wg0 & 7) * 64 + (wg0 >> 3);
    const int bm = (wg >> 5) * 256;
    const int bn = (wg & 31) * 256;
    const int K = QKV_K;

    // staging: round r covers rows [r*64, r*64+64); this thread supplies
    // row r*64 + wave*8 + (lane>>3), source col pre-swizzled by the
    // involution colbyte ^ ((row&7)<<4)  (row&7 == lane>>3 here).
    const int srow = wave * 8 + (lane >> 3);
    const int scu = ((lane & 7) ^ (lane >> 3)) << 3;   // u16 units
    const u16* gA = A + (size_t)(bm + srow) * K + scu;
    const u16* gB = B + (size_t)(bn + srow) * K + scu;

    floatx4 acc[8][4];
#pragma unroll
    for (int i = 0; i < 8; ++i)
#pragma unroll
        for (int j = 0; j < 4; ++j) acc[i][j] = (floatx4){0.f, 0.f, 0.f, 0.f};

#define STG(tt, bb)                                                           \
    {                                                                         \
        const int k0_ = (tt) * 64;                                            \
        _Pragma("unroll")                                                     \
        for (int r2 = 0; r2 < 4; ++r2) {                                      \
            gload16(gA + k0_ + (size_t)(r2 * 64) * K,                         \
                    &As[(bb) * 16384 + r2 * 4096 + wave * 512]);              \
            gload16(gB + k0_ + (size_t)(r2 * 64) * K,                         \
                    &Bs[(bb) * 16384 + r2 * 4096 + wave * 512]);              \
        }                                                                     \
    }

    STG(0, 0);   // prologue: 8 loads in flight

    for (int t = 0; t < QKV_NT; ++t) {
        const int cb = t & 1;
        if (t + 1 < QKV_NT) {
            STG(t + 1, cb ^ 1);                       // +8 -> 16 outstanding
            asm volatile("s_waitcnt vmcnt(8)" ::: "memory");  // tile t landed
        } else {
            asm volatile("s_waitcnt vmcnt(0)" ::: "memory");  // final drain
        }
        __builtin_amdgcn_sched_barrier(0);
        __builtin_amdgcn_s_barrier();                 // all waves: tile t resident
        __builtin_amdgcn_sched_barrier(0);

#pragma unroll
        for (int kk = 0; kk < 2; ++kk) {
            half8 bq[4], aq[8];
#pragma unroll
            for (int j = 0; j < 4; ++j)
                bq[j] = *(const half8*)(&Bs[cb * 16384 + (wc * 64 + j * 16 + l16) * 64 +
                                            ((kk * 32 + quad * 8) ^ ((l16 & 7) << 3))]);
#pragma unroll
            for (int i = 0; i < 8; ++i)
                aq[i] = *(const half8*)(&As[cb * 16384 + (wr * 128 + i * 16 + l16) * 64 +
                                            ((kk * 32 + quad * 8) ^ ((l16 & 7) << 3))]);
#pragma unroll
            for (int i = 0; i < 8; ++i)
#pragma unroll
                for (int j = 0; j < 4; ++j)
                    acc[i][j] = __builtin_amdgcn_mfma_f32_16x16x32_f16(aq[i], bq[j], acc[i][j], 0, 0, 0);
        }

        __builtin_amdgcn_sched_barrier(0);
        __builtin_amdgcn_s_barrier();   // reads of buf cb done before overwrite
        __builtin_amdgcn_sched_barrier(0);
    }
#undef STG

    // epilogue: row = bm + wr*128 + i*16 + quad*4 + r,
    //           col = bn + wc*64 + j*16 + l16. Region boundaries (4096, 6144)
    //           are multiples of 256 -> block-uniform routing.
#pragma unroll
    for (int i = 0; i < 8; ++i) {
#pragma unroll
        for (int j = 0; j < 4; ++j) {
            const int row0 = bm + wr * 128 + i * 16 + quad * 4;
            const int col = bn + wc * 64 + j * 16 + l16;
#pragma unroll
            for (int r = 0; r < 4; ++r) {
                const u16 hv = f2h(acc[i][j][r]);
                if (bn < 4096)
                    Qb[(size_t)(row0 + r) * QD + col] = hv;
                else if (bn < 6144)
                    Kb[(size_t)(row0 + r) * KVD + (col - 4096)] = hv;
                else
                    Vt[(size_t)(col - 6144) * TOKS + row0 + r] = hv;
            }
        }
    }
}

// ---------------------------------------------------------------------------
// Generic 128x128 GEMM (m97 structure): C[M,N] = A[M,K]*B[N,K]^T, f16 in,
// f32 accum, linear LDS staged via global_load_lds. XCD swizzle when
// nwg % 8 == 0. Used for the output projection.
// ---------------------------------------------------------------------------
template<bool OUTF32>
__global__ __launch_bounds__(256) void gemm_lds(const u16* __restrict__ A,
                                                const u16* __restrict__ B,
                                                void* __restrict__ Cp,
                                                int M, int N, int K) {
    __shared__ u16 As[128 * 32];
    __shared__ u16 Bs[128 * 32];

    const int tid = threadIdx.x;
    const int wave = tid >> 6, lane = tid & 63;
    const int quad = lane >> 4, l16 = lane & 15;

    int wg = blockIdx.y * gridDim.x + blockIdx.x;
    const int nwg = gridDim.x * gridDim.y;
    if ((nwg & 7) == 0) wg = (wg & 7) * (nwg >> 3) + (wg >> 3);
    const int bm = (wg / gridDim.x) * 128, bn = (wg % gridDim.x) * 128;
    const int wm = (wave >> 1) * 64, wn = (wave & 1) * 64;

    const int srow = wave * 32 + (lane >> 2);
    const int scol = (lane & 3) * 8;
    const u16* ga0 = A + (size_t)(bm + srow) * K + scol;
    const u16* ga1 = ga0 + (size_t)16 * K;
    const u16* gb0 = B + (size_t)(bn + srow) * K + scol;
    const u16* gb1 = gb0 + (size_t)16 * K;
    u16* lA0 = &As[wave * 1024];
    u16* lA1 = &As[wave * 1024 + 512];
    u16* lB0 = &Bs[wave * 1024];
    u16* lB1 = &Bs[wave * 1024 + 512];

    floatx4 acc[4][4];
#pragma unroll
    for (int i = 0; i < 4; ++i)
#pragma unroll
        for (int j = 0; j < 4; ++j) acc[i][j] = (floatx4){0.f, 0.f, 0.f, 0.f};

    const int kTiles = K >> 5;
    for (int kt = 0; kt < kTiles; ++kt) {
        __syncthreads();
        gload16(ga0, lA0);
        gload16(ga1, lA1);
        gload16(gb0, lB0);
        gload16(gb1, lB1);
        ga0 += 32; ga1 += 32; gb0 += 32; gb1 += 32;
        __syncthreads();

        half8 af[4], bfr[4];
#pragma unroll
        for (int i = 0; i < 4; ++i)
            af[i] = *(const half8*)(&As[(wm + i * 16 + l16) * 32 + quad * 8]);
#pragma unroll
        for (int j = 0; j < 4; ++j)
            bfr[j] = *(const half8*)(&Bs[(wn + j * 16 + l16) * 32 + quad * 8]);
#pragma unroll
        for (int i = 0; i < 4; ++i)
#pragma unroll
            for (int j = 0; j < 4; ++j)
                acc[i][j] = __builtin_amdgcn_mfma_f32_16x16x32_f16(af[i], bfr[j], acc[i][j], 0, 0, 0);
    }

#pragma unroll
    for (int i = 0; i < 4; ++i) {
#pragma unroll
        for (int j = 0; j < 4; ++j) {
            const int row0 = bm + wm + i * 16 + quad * 4;
            const int col = bn + wn + j * 16 + l16;
#pragma unroll
            for (int r = 0; r < 4; ++r) {
                if constexpr (OUTF32)
                    ((float*)Cp)[(size_t)(row0 + r) * N + col] = acc[i][j][r];
                else
                    ((u16*)Cp)[(size_t)(row0 + r) * N + col] = f2h(acc[i][j][r]);
            }
        }
    }
}

// ---------------------------------------------------------------------------
// Fused per-head RMSNorm (+weight) and RoPE for Q and K. One wave per
// (row, head-slot). slots: 0..15 Q heads, 16..23 K heads. In-place (f16).
// ---------------------------------------------------------------------------
__global__ __launch_bounds__(256) void norm_rope_kernel(
        u16* __restrict__ Q, u16* __restrict__ K,
        const float* __restrict__ qw, const float* __restrict__ kw,
        const float* __restrict__ cosp, const float* __restrict__ sinp) {
    const int w = blockIdx.x * 4 + (threadIdx.x >> 6);
    const int lane = threadIdx.x & 63;
    const int row = w >> 5;   // 0..4095 (= b*2048+s)
    const int sub = w & 31;
    if (sub >= 24) return;    // V handled by vnorm_kernel on V^T

    u16* ptr;
    const float* wt;
    if (sub < 16) { ptr = Q + (size_t)row * QD + sub * HD;         wt = qw; }
    else          { ptr = K + (size_t)row * KVD + (sub - 16) * HD; wt = kw; }

    const int d = lane * 4;
    uint2 raw = *(const uint2*)(ptr + d);
    float x[4];
    x[0] = h2f((u16)(raw.x & 0xffffu));
    x[1] = h2f((u16)(raw.x >> 16));
    x[2] = h2f((u16)(raw.y & 0xffffu));
    x[3] = h2f((u16)(raw.y >> 16));

    float ss = x[0] * x[0] + x[1] * x[1] + x[2] * x[2] + x[3] * x[3];
#pragma unroll
    for (int m = 1; m < 64; m <<= 1) ss += __shfl_xor(ss, m, 64);
    const float sc = rsqrtf(ss * (1.0f / 256.0f) + 1e-6f);

    float nrm[4];
#pragma unroll
    for (int i = 0; i < 4; ++i) nrm[i] = x[i] * sc * wt[d + i];

    const size_t cbase = (size_t)row * HD + d;
    const float sgn = (lane < 32) ? -1.0f : 1.0f;
    float out[4];
#pragma unroll
    for (int i = 0; i < 4; ++i) {
        float pn = __shfl_xor(nrm[i], 32, 64);  // partner holds d±128
        float c = cosp[cbase + i];
        float s = sinp[cbase + i];
        out[i] = nrm[i] * c + sgn * pn * s;
    }

    uint2 o;
    o.x = (unsigned int)f2h(out[0]) | ((unsigned int)f2h(out[1]) << 16);
    o.y = (unsigned int)f2h(out[2]) | ((unsigned int)f2h(out[3]) << 16);
    *(uint2*)(ptr + d) = o;
}

// ---------------------------------------------------------------------------
// RMSNorm (weight = 1) of V, in place on V^T[KVD][TOKS].
// ---------------------------------------------------------------------------
__global__ __launch_bounds__(256) void vnorm_kernel(u16* __restrict__ Vt) {
    const int tok = blockIdx.x * 256 + threadIdx.x;  // 0..4095
    const int kvh = blockIdx.y;
    u16* p = Vt + (size_t)kvh * HD * TOKS + tok;
    float ss = 0.f;
#pragma unroll 4
    for (int d = 0; d < HD; ++d) {
        float v = h2f(p[(size_t)d * TOKS]);
        ss += v * v;
    }
    const float sc = rsqrtf(ss * (1.0f / 256.0f) + 1e-6f);
#pragma unroll 4
    for (int d = 0; d < HD; ++d) {
        const size_t idx = (size_t)d * TOKS;
        p[idx] = f2h(h2f(p[idx]) * sc);
    }
}

// ---------------------------------------------------------------------------
// MFMA flash attention, sliding window (unchanged from round 3).
// ---------------------------------------------------------------------------
#define QBLK 64
#define KVBLK 64

__global__ __launch_bounds__(256, 2) void attn_mfma(
        const u16* __restrict__ Q, const u16* __restrict__ K,
        const u16* __restrict__ Vt, u16* __restrict__ O) {
    __shared__ u16 Ks[64 * 256];      // 32768 B, row = key token, 512B/row
    __shared__ u16 Vs[256 * 64];      // 32768 B, row = dim d, 128B/row
    __shared__ u16 Ps[4][16 * 72];    //  9216 B  (total 74752 B -> 2 blk/CU)

    const int tid = threadIdx.x;
    const int wave = tid >> 6, lane = tid & 63;
    const int quad = lane >> 4, l16 = lane & 15;
    const int q0 = blockIdx.x * QBLK;
    const int h = blockIdx.y, b = blockIdx.z;
    const int kvh = h >> 1;  // jnp.repeat(k, 2, axis=2)

    // Q fragments: A-operand row = l16, k = s*32 + quad*8
    half8 qf[8];
    {
        const u16* qp = Q + (size_t)(b * SEQ + q0 + wave * 16 + l16) * QD + h * HD + quad * 8;
#pragma unroll
        for (int s = 0; s < 8; ++s) qf[s] = *(const half8*)(qp + s * 32);
    }

    float mrow[4], lrow[4];
#pragma unroll
    for (int r = 0; r < 4; ++r) { mrow[r] = -1e30f; lrow[r] = 0.f; }
    floatx4 o[16];
#pragma unroll
    for (int n = 0; n < 16; ++n) o[n] = (floatx4){0.f, 0.f, 0.f, 0.f};

    int lo = q0 - (WINDOW - 1);
    const int t0 = (lo > 0 ? lo : 0) >> 6;
    const int tq = q0 >> 6;

    // per-lane staging constants
    const int kr2 = wave * 2 + (lane >> 5);        // K: row within 2-row group
    const int kcb = (lane & 31) * 16;              // K: stored col byte
    const int vr8 = wave * 8 + (lane >> 3);        // V: row within 8-row group
    const int vcb = (lane & 7) * 16;               // V: stored col byte

    for (int t = t0; t <= tq; ++t) {
        const int k0 = t * KVBLK;
        __syncthreads();  // previous iteration's LDS reads complete
        // async stage K tile [64 tok][256 d], pre-swizzled source
#pragma unroll
        for (int p = 0; p < 8; ++p) {
            const int row = p * 8 + kr2;
            const int scb = kcb ^ ((row & 7) << 4);
            const u16* g = K + (size_t)(b * SEQ + k0 + row) * KVD + kvh * HD + (scb >> 1);
            gload16(g, &Ks[p * 2048 + wave * 512]);
        }
        // async stage V^T tile [256 d][64 tok], pre-swizzled source
#pragma unroll
        for (int p = 0; p < 8; ++p) {
            const int row = p * 32 + vr8;
            const int scb = vcb ^ ((row & 7) << 4);
            const u16* g = Vt + (size_t)(kvh * HD + row) * TOKS + b * SEQ + k0 + (scb >> 1);
            gload16(g, &Vs[p * 2048 + wave * 512]);
        }
        __syncthreads();  // vmcnt(0) drain: both tiles resident

        // QK^T: S[16q][64k], f32 accum
        floatx4 sf[4];
#pragma unroll
        for (int j = 0; j < 4; ++j) sf[j] = (floatx4){0.f, 0.f, 0.f, 0.f};
        __builtin_amdgcn_s_setprio(1);
#pragma unroll
        for (int s = 0; s < 8; ++s) {
#pragma unroll
            for (int j = 0; j < 4; ++j) {
                half8 bf = *(const half8*)(&Ks[(j * 16 + l16) * 256 +
                                               ((s * 32 + quad * 8) ^ ((l16 & 7) << 3))]);
                sf[j] = __builtin_amdgcn_mfma_f32_16x16x32_f16(qf[s], bf, sf[j], 0, 0, 0);
            }
        }
        __builtin_amdgcn_s_setprio(0);

        // mask (diagonal tile and/or window-trailing-edge tile only)
        const bool needMask = (t == tq) || ((q0 + QBLK - 1) - k0 >= WINDOW);
        if (needMask) {
#pragma unroll
            for (int j = 0; j < 4; ++j) {
                const int kg = k0 + j * 16 + l16;
#pragma unroll
                for (int r = 0; r < 4; ++r) {
                    const int qg = q0 + wave * 16 + quad * 4 + r;
                    if (kg > qg || qg - kg >= WINDOW) sf[j][r] = -1e30f;
                }
            }
        }

        // online softmax; row r lives in the 16 lanes of this quad
#pragma unroll
        for (int r = 0; r < 4; ++r) {
            float mx = fmaxf(fmaxf(sf[0][r], sf[1][r]), fmaxf(sf[2][r], sf[3][r]));
            mx = fmaxf(mx, __shfl_xor(mx, 1, 64));
            mx = fmaxf(mx, __shfl_xor(mx, 2, 64));
            mx = fmaxf(mx, __shfl_xor(mx, 4, 64));
            mx = fmaxf(mx, __shfl_xor(mx, 8, 64));
            const float mnew = fmaxf(mrow[r], mx);
            const float rescale = __expf(mrow[r] - mnew);
            mrow[r] = mnew;
            float pv[4], ssum = 0.f;
#pragma unroll
            for (int j = 0; j < 4; ++j) {
                pv[j] = __expf(sf[j][r] - mnew);
                ssum += pv[j];
            }
            ssum += __shfl_xor(ssum, 1, 64);
            ssum += __shfl_xor(ssum, 2, 64);
            ssum += __shfl_xor(ssum, 4, 64);
            ssum += __shfl_xor(ssum, 8, 64);
            lrow[r] = lrow[r] * rescale + ssum;
#pragma unroll
            for (int n = 0; n < 16; ++n) o[n][r] *= rescale;
#pragma unroll
            for (int j = 0; j < 4; ++j)
                Ps[wave][(quad * 4 + r) * 72 + j * 16 + l16] = f2h(pv[j]);
        }

        // PV: O[16q][256d] += P[16q][64k] * V[64k][256d]
        __builtin_amdgcn_s_setprio(1);
#pragma unroll
        for (int s2 = 0; s2 < 2; ++s2) {
            half8 pa = *(const half8*)(&Ps[wave][l16 * 72 + s2 * 32 + quad * 8]);
#pragma unroll
            for (int n = 0; n < 16; ++n) {
                half8 vb = *(const half8*)(&Vs[(n * 16 + l16) * 64 +
                                               ((s2 * 32 + quad * 8) ^ ((l16 & 7) << 3))]);
                o[n] = __builtin_amdgcn_mfma_f32_16x16x32_f16(pa, vb, o[n], 0, 0, 0);
            }
        }
        __builtin_amdgcn_s_setprio(0);
    }

    // epilogue: row = q0+wave*16+quad*4+r, col = h*HD + n*16 + l16
#pragma unroll
    for (int r = 0; r < 4; ++r) {
        const float inv = 1.0f / lrow[r];
        const size_t base = (size_t)(b * SEQ + q0 + wave * 16 + quad * 4 + r) * QD + h * HD + l16;
#pragma unroll
        for (int n = 0; n < 16; ++n)
            O[base + n * 16] = f2h(o[n][r] * inv);
    }
}

// ---------------------------------------------------------------------------
// Workspace plan (ws proven >= 100,663,296 B by previous rounds):
//   ws[ 0,32M)  Qb (qkv gemm..attn); then Woh f16 23.07M (after attn)
//   ws[32,48M)  Kb
//   ws[48,64M)  Vt (V^T [2048][4096])
//   ws[64,96M)  Xh f16 23.07M (dead after qkv gemm) -> then Ob (attn out)
//   d_out (46,137,344 B): Wqkv f16 [8192][2816] = exactly out_size; dead
//   before the final gemm overwrites d_out.
// ---------------------------------------------------------------------------
extern "C" void kernel_launch(void* const* d_in, const int* in_sizes, int n_in,
                              void* d_out, int out_size, void* d_ws, size_t ws_size,
                              hipStream_t stream) {
    const float* X    = (const float*)d_in[0];   // (2,2048,2816) f32
    const float* Wq   = (const float*)d_in[1];   // (4096,2816) f32
    const float* Wk   = (const float*)d_in[2];   // (2048,2816) f32
    const float* Wv   = (const float*)d_in[3];   // (2048,2816) f32
    const float* Wo   = (const float*)d_in[4];   // (2816,4096) f32
    const float* qw   = (const float*)d_in[5];   // (256,) f32
    const float* kw   = (const float*)d_in[6];   // (256,) f32
    const float* cosp = (const float*)d_in[7];   // (2,2048,256) f32
    const float* sinp = (const float*)d_in[8];   // (2,2048,256) f32

    char* ws = (char*)d_ws;
    u16* Qb  = (u16*)(ws);                        // 32 MB
    u16* Kb  = (u16*)(ws + (size_t)33554432);     // 16 MB
    u16* Vt  = (u16*)(ws + (size_t)50331648);     // V^T 16 MB
    u16* Xh  = (u16*)(ws + (size_t)67108864);     // 23.07 MB, dead after qkv
    u16* Ob  = (u16*)(ws + (size_t)67108864);     // 32 MB (attn output)
    u16* Woh = (u16*)(ws);                        // 23.07 MB, after attn

    u16* Wqkv = (u16*)d_out;                      // [8192][2816] f16 = 46.14 MB

    const dim3 blk(256);
    f32_to_f16<<<dim3(5632), blk, 0, stream>>>(X,  Xh, 11534336 / 8);
    f32_to_f16<<<dim3(5632), blk, 0, stream>>>(Wq, Wqkv, 11534336 / 8);
    f32_to_f16<<<dim3(2816), blk, 0, stream>>>(Wk, Wqkv + (size_t)4096 * 2816, 5767168 / 8);
    f32_to_f16<<<dim3(2816), blk, 0, stream>>>(Wv, Wqkv + (size_t)6144 * 2816, 5767168 / 8);
    gemm256_qkv<<<dim3(512), dim3(512), 0, stream>>>(Xh, Wqkv, Qb, Kb, Vt);
    norm_rope_kernel<<<dim3((BATCH * SEQ * 32) / 4), blk, 0, stream>>>(Qb, Kb, qw, kw, cosp, sinp);
    vnorm_kernel<<<dim3(TOKS / 256, NKV), blk, 0, stream>>>(Vt);
    attn_mfma<<<dim3(SEQ / QBLK, NH, BATCH), blk, 0, stream>>>(Qb, Kb, Vt, Ob);
    f32_to_f16<<<dim3(5632), blk, 0, stream>>>(Wo, Woh, 11534336 / 8);
    gemm_lds<true><<<dim3(2816 / 128, 4096 / 128), blk, 0, stream>>>(Ob, Woh, d_out, 4096, 2816, 4096);
}

// Round 5
// 731.856 us; speedup vs baseline: 12.8464x; 1.0643x over previous
//
#include <hip/hip_runtime.h>
#include <math.h>

typedef unsigned short u16;
typedef __attribute__((ext_vector_type(8))) short short8;
typedef __attribute__((ext_vector_type(8))) _Float16 half8;
typedef __attribute__((ext_vector_type(4))) float floatx4;

#define NH 16
#define NKV 8
#define HD 256
#define SEQ 2048
#define BATCH 2
#define QD (NH * HD)    // 4096
#define KVD (NKV * HD)  // 2048
#define TOKS (BATCH * SEQ)  // 4096
#define WINDOW 1024

__device__ __forceinline__ u16 f2h(float f) {
    _Float16 h = (_Float16)f;
    return __builtin_bit_cast(u16, h);
}
__device__ __forceinline__ float h2f(u16 u) {
    return (float)__builtin_bit_cast(_Float16, u);
}

// async global->LDS, 16B per lane. lds ptr is wave-uniform; HW deposits at
// lds + lane*16. global ptr is per-lane (enables pre-swizzled sources).
__device__ __forceinline__ void gload16(const u16* g, u16* l) {
    __builtin_amdgcn_global_load_lds(
        (const __attribute__((address_space(1))) unsigned int*)g,
        (__attribute__((address_space(3))) unsigned int*)l,
        16, 0, 0);
}

// ---------------------------------------------------------------------------
// f32 -> f16 conversion, 8 elem/thread, fully vectorized.
// ---------------------------------------------------------------------------
__global__ __launch_bounds__(256) void f32_to_f16(const float* __restrict__ in,
                                                  u16* __restrict__ out, int n8) {
    const int i = blockIdx.x * 256 + threadIdx.x;
    if (i >= n8) return;
    const float4 a = *((const float4*)in + 2 * (size_t)i);
    const float4 b = *((const float4*)in + 2 * (size_t)i + 1);
    short8 r;
    r[0] = (short)f2h(a.x); r[1] = (short)f2h(a.y);
    r[2] = (short)f2h(a.z); r[3] = (short)f2h(a.w);
    r[4] = (short)f2h(b.x); r[5] = (short)f2h(b.y);
    r[6] = (short)f2h(b.z); r[7] = (short)f2h(b.w);
    *((short8*)out + i) = r;
}

// ---------------------------------------------------------------------------
// 256x128xBK32 double-buffered GEMM, 2 blocks/CU (m114 inter-block overlap).
// C[M,N] = A[M,K]*B[N,K]^T, f16 in, f32 accum. 512 thr = 8 waves (4M x 2N),
// per-wave 64x64 output -> acc = 64 regs, combined regs <= 128 so TWO blocks
// co-reside (16 waves/CU): while one block sits in its barrier/DS burst the
// other feeds the MFMA pipe.
// LDS 48 KB: As [2][256][32] u16, Bs [2][128][32] u16. 64B rows: XOR-swizzle
// 16B-slot by ((row>>1)&3) -> exactly 2 lanes/bank (free). Involution applied
// BOTH sides: staged global col (lane&3)^((lane>>3)&3), read slot
// quad^((l16>>1)&3)  (rule #21).
// Sync per tile (verified round-4 skeleton): STG(t+1) -> vmcnt(3) [tile t
// landed, t+1 in flight] -> s_barrier -> compute -> s_barrier.
// MODE 0: QKV 3-way routed f16 output (V region transposed -> V^T).
// MODE 1: f32 C.
// Requirements: M % 256 == 0, N % 128 == 0, K % 32 == 0, grid % 8 == 0.
// ---------------------------------------------------------------------------
template<int MODE>
__global__ __launch_bounds__(512, 4) void gemm_db(
        const u16* __restrict__ A, const u16* __restrict__ B,
        void* __restrict__ Cq, void* __restrict__ Ck, void* __restrict__ Cv,
        int N, int K, int ntn) {
    __shared__ u16 As[2 * 8192];   // 2 x 16 KB
    __shared__ u16 Bs[2 * 4096];   // 2 x  8 KB

    const int tid = threadIdx.x;
    const int wave = tid >> 6, lane = tid & 63;
    const int quad = lane >> 4, l16 = lane & 15;
    const int wr = wave >> 1, wc = wave & 1;

    // XCD-bijective swizzle (grid % 8 == 0)
    const int nwg = (int)gridDim.x;
    const int wg0 = (int)blockIdx.x;
    const int wg = (wg0 & 7) * (nwg >> 3) + (wg0 >> 3);
    const int bm = (wg / ntn) * 256;
    const int bn = (wg % ntn) * 128;

    // staging: per tile 3 gload16/thread. A chunks: wave w -> rows
    // [32w,32w+16) and [32w+16,32w+32); B: wave w -> rows [16w,16w+16).
    // lane l supplies chunk-row l>>2, source 16B-slot (l&3)^((l>>3)&3)
    // (pre-swizzled so the linear LDS deposit realizes the read swizzle).
    const int lrow = lane >> 2;
    const int lcol = (((lane & 3) ^ ((lane >> 3) & 3)) << 3);  // u16 units
    const u16* gA  = A + (size_t)(bm + wave * 32 + lrow) * K + lcol;
    const u16* gA2 = gA + (size_t)16 * K;
    const u16* gB  = B + (size_t)(bn + wave * 16 + lrow) * K + lcol;

    floatx4 acc[4][4];
#pragma unroll
    for (int i = 0; i < 4; ++i)
#pragma unroll
        for (int j = 0; j < 4; ++j) acc[i][j] = (floatx4){0.f, 0.f, 0.f, 0.f};

#define STG(tt, bb)                                                           \
    {                                                                         \
        const int ko_ = (tt) << 5;                                            \
        gload16(gA + ko_,  &As[(bb) * 8192 + wave * 1024]);                   \
        gload16(gA2 + ko_, &As[(bb) * 8192 + wave * 1024 + 512]);             \
        gload16(gB + ko_,  &Bs[(bb) * 4096 + wave * 512]);                    \
    }

    STG(0, 0);   // prologue: 3 loads in flight

    // swizzled read slot, uniform across i/j: (row>>1)&3 == (l16>>1)&3 here
    const int rdsw = ((quad ^ ((l16 >> 1) & 3)) << 3);
    const int aoff = (wr * 64 + l16) * 32 + rdsw;
    const int boff = (wc * 64 + l16) * 32 + rdsw;

    const int NT = K >> 5;
    for (int t = 0; t < NT; ++t) {
        const int cb = t & 1;
        if (t + 1 < NT) {
            STG(t + 1, cb ^ 1);                       // +3 -> 6 outstanding
            asm volatile("s_waitcnt vmcnt(3)" ::: "memory");  // tile t landed
        } else {
            asm volatile("s_waitcnt vmcnt(0)" ::: "memory");  // final drain
        }
        __builtin_amdgcn_sched_barrier(0);
        __builtin_amdgcn_s_barrier();                 // tile t resident
        __builtin_amdgcn_sched_barrier(0);

        half8 aq[4], bq[4];
#pragma unroll
        for (int i = 0; i < 4; ++i)
            aq[i] = *(const half8*)(&As[cb * 8192 + aoff + i * 512]);
#pragma unroll
        for (int j = 0; j < 4; ++j)
            bq[j] = *(const half8*)(&Bs[cb * 4096 + boff + j * 512]);
#pragma unroll
        for (int i = 0; i < 4; ++i)
#pragma unroll
            for (int j = 0; j < 4; ++j)
                acc[i][j] = __builtin_amdgcn_mfma_f32_16x16x32_f16(aq[i], bq[j], acc[i][j], 0, 0, 0);

        __builtin_amdgcn_sched_barrier(0);
        __builtin_amdgcn_s_barrier();   // reads of buf cb done before overwrite
        __builtin_amdgcn_sched_barrier(0);
    }
#undef STG

    // epilogue: row = bm + wr*64 + i*16 + quad*4 + r, col = bn + wc*64 + j*16
    // + l16. MODE 0 region boundaries (4096, 6144) are multiples of 128.
#pragma unroll
    for (int i = 0; i < 4; ++i) {
#pragma unroll
        for (int j = 0; j < 4; ++j) {
            const int row0 = bm + wr * 64 + i * 16 + quad * 4;
            const int col = bn + wc * 64 + j * 16 + l16;
#pragma unroll
            for (int r = 0; r < 4; ++r) {
                if constexpr (MODE == 1) {
                    ((float*)Cq)[(size_t)(row0 + r) * N + col] = acc[i][j][r];
                } else {
                    const u16 hv = f2h(acc[i][j][r]);
                    if (bn < 4096)
                        ((u16*)Cq)[(size_t)(row0 + r) * QD + col] = hv;
                    else if (bn < 6144)
                        ((u16*)Ck)[(size_t)(row0 + r) * KVD + (col - 4096)] = hv;
                    else
                        ((u16*)Cv)[(size_t)(col - 6144) * TOKS + row0 + r] = hv;
                }
            }
        }
    }
}

// ---------------------------------------------------------------------------
// Fused per-head RMSNorm (+weight) and RoPE for Q and K. One wave per
// (row, head-slot). slots: 0..15 Q heads, 16..23 K heads. In-place (f16).
// ---------------------------------------------------------------------------
__global__ __launch_bounds__(256) void norm_rope_kernel(
        u16* __restrict__ Q, u16* __restrict__ K,
        const float* __restrict__ qw, const float* __restrict__ kw,
        const float* __restrict__ cosp, const float* __restrict__ sinp) {
    const int w = blockIdx.x * 4 + (threadIdx.x >> 6);
    const int lane = threadIdx.x & 63;
    const int row = w >> 5;   // 0..4095 (= b*2048+s)
    const int sub = w & 31;
    if (sub >= 24) return;    // V handled by vnorm_kernel on V^T

    u16* ptr;
    const float* wt;
    if (sub < 16) { ptr = Q + (size_t)row * QD + sub * HD;         wt = qw; }
    else          { ptr = K + (size_t)row * KVD + (sub - 16) * HD; wt = kw; }

    const int d = lane * 4;
    uint2 raw = *(const uint2*)(ptr + d);
    float x[4];
    x[0] = h2f((u16)(raw.x & 0xffffu));
    x[1] = h2f((u16)(raw.x >> 16));
    x[2] = h2f((u16)(raw.y & 0xffffu));
    x[3] = h2f((u16)(raw.y >> 16));

    float ss = x[0] * x[0] + x[1] * x[1] + x[2] * x[2] + x[3] * x[3];
#pragma unroll
    for (int m = 1; m < 64; m <<= 1) ss += __shfl_xor(ss, m, 64);
    const float sc = rsqrtf(ss * (1.0f / 256.0f) + 1e-6f);

    float nrm[4];
#pragma unroll
    for (int i = 0; i < 4; ++i) nrm[i] = x[i] * sc * wt[d + i];

    const size_t cbase = (size_t)row * HD + d;
    const float sgn = (lane < 32) ? -1.0f : 1.0f;
    float out[4];
#pragma unroll
    for (int i = 0; i < 4; ++i) {
        float pn = __shfl_xor(nrm[i], 32, 64);  // partner holds d±128
        float c = cosp[cbase + i];
        float s = sinp[cbase + i];
        out[i] = nrm[i] * c + sgn * pn * s;
    }

    uint2 o;
    o.x = (unsigned int)f2h(out[0]) | ((unsigned int)f2h(out[1]) << 16);
    o.y = (unsigned int)f2h(out[2]) | ((unsigned int)f2h(out[3]) << 16);
    *(uint2*)(ptr + d) = o;
}

// ---------------------------------------------------------------------------
// RMSNorm (weight = 1) of V, in place on V^T[KVD][TOKS].
// ---------------------------------------------------------------------------
__global__ __launch_bounds__(256) void vnorm_kernel(u16* __restrict__ Vt) {
    const int tok = blockIdx.x * 256 + threadIdx.x;  // 0..4095
    const int kvh = blockIdx.y;
    u16* p = Vt + (size_t)kvh * HD * TOKS + tok;
    float ss = 0.f;
#pragma unroll 4
    for (int d = 0; d < HD; ++d) {
        float v = h2f(p[(size_t)d * TOKS]);
        ss += v * v;
    }
    const float sc = rsqrtf(ss * (1.0f / 256.0f) + 1e-6f);
#pragma unroll 4
    for (int d = 0; d < HD; ++d) {
        const size_t idx = (size_t)d * TOKS;
        p[idx] = f2h(h2f(p[idx]) * sc);
    }
}

// ---------------------------------------------------------------------------
// MFMA flash attention, sliding window (unchanged from round 3/4).
// ---------------------------------------------------------------------------
#define QBLK 64
#define KVBLK 64

__global__ __launch_bounds__(256, 2) void attn_mfma(
        const u16* __restrict__ Q, const u16* __restrict__ K,
        const u16* __restrict__ Vt, u16* __restrict__ O) {
    __shared__ u16 Ks[64 * 256];      // 32768 B, row = key token, 512B/row
    __shared__ u16 Vs[256 * 64];      // 32768 B, row = dim d, 128B/row
    __shared__ u16 Ps[4][16 * 72];    //  9216 B  (total 74752 B -> 2 blk/CU)

    const int tid = threadIdx.x;
    const int wave = tid >> 6, lane = tid & 63;
    const int quad = lane >> 4, l16 = lane & 15;
    const int q0 = blockIdx.x * QBLK;
    const int h = blockIdx.y, b = blockIdx.z;
    const int kvh = h >> 1;  // jnp.repeat(k, 2, axis=2)

    // Q fragments: A-operand row = l16, k = s*32 + quad*8
    half8 qf[8];
    {
        const u16* qp = Q + (size_t)(b * SEQ + q0 + wave * 16 + l16) * QD + h * HD + quad * 8;
#pragma unroll
        for (int s = 0; s < 8; ++s) qf[s] = *(const half8*)(qp + s * 32);
    }

    float mrow[4], lrow[4];
#pragma unroll
    for (int r = 0; r < 4; ++r) { mrow[r] = -1e30f; lrow[r] = 0.f; }
    floatx4 o[16];
#pragma unroll
    for (int n = 0; n < 16; ++n) o[n] = (floatx4){0.f, 0.f, 0.f, 0.f};

    int lo = q0 - (WINDOW - 1);
    const int t0 = (lo > 0 ? lo : 0) >> 6;
    const int tq = q0 >> 6;

    // per-lane staging constants
    const int kr2 = wave * 2 + (lane >> 5);        // K: row within 2-row group
    const int kcb = (lane & 31) * 16;              // K: stored col byte
    const int vr8 = wave * 8 + (lane >> 3);        // V: row within 8-row group
    const int vcb = (lane & 7) * 16;               // V: stored col byte

    for (int t = t0; t <= tq; ++t) {
        const int k0 = t * KVBLK;
        __syncthreads();  // previous iteration's LDS reads complete
        // async stage K tile [64 tok][256 d], pre-swizzled source
#pragma unroll
        for (int p = 0; p < 8; ++p) {
            const int row = p * 8 + kr2;
            const int scb = kcb ^ ((row & 7) << 4);
            const u16* g = K + (size_t)(b * SEQ + k0 + row) * KVD + kvh * HD + (scb >> 1);
            gload16(g, &Ks[p * 2048 + wave * 512]);
        }
        // async stage V^T tile [256 d][64 tok], pre-swizzled source
#pragma unroll
        for (int p = 0; p < 8; ++p) {
            const int row = p * 32 + vr8;
            const int scb = vcb ^ ((row & 7) << 4);
            const u16* g = Vt + (size_t)(kvh * HD + row) * TOKS + b * SEQ + k0 + (scb >> 1);
            gload16(g, &Vs[p * 2048 + wave * 512]);
        }
        __syncthreads();  // vmcnt(0) drain: both tiles resident

        // QK^T: S[16q][64k], f32 accum
        floatx4 sf[4];
#pragma unroll
        for (int j = 0; j < 4; ++j) sf[j] = (floatx4){0.f, 0.f, 0.f, 0.f};
        __builtin_amdgcn_s_setprio(1);
#pragma unroll
        for (int s = 0; s < 8; ++s) {
#pragma unroll
            for (int j = 0; j < 4; ++j) {
                half8 bf = *(const half8*)(&Ks[(j * 16 + l16) * 256 +
                                               ((s * 32 + quad * 8) ^ ((l16 & 7) << 3))]);
                sf[j] = __builtin_amdgcn_mfma_f32_16x16x32_f16(qf[s], bf, sf[j], 0, 0, 0);
            }
        }
        __builtin_amdgcn_s_setprio(0);

        // mask (diagonal tile and/or window-trailing-edge tile only)
        const bool needMask = (t == tq) || ((q0 + QBLK - 1) - k0 >= WINDOW);
        if (needMask) {
#pragma unroll
            for (int j = 0; j < 4; ++j) {
                const int kg = k0 + j * 16 + l16;
#pragma unroll
                for (int r = 0; r < 4; ++r) {
                    const int qg = q0 + wave * 16 + quad * 4 + r;
                    if (kg > qg || qg - kg >= WINDOW) sf[j][r] = -1e30f;
                }
            }
        }

        // online softmax; row r lives in the 16 lanes of this quad
#pragma unroll
        for (int r = 0; r < 4; ++r) {
            float mx = fmaxf(fmaxf(sf[0][r], sf[1][r]), fmaxf(sf[2][r], sf[3][r]));
            mx = fmaxf(mx, __shfl_xor(mx, 1, 64));
            mx = fmaxf(mx, __shfl_xor(mx, 2, 64));
            mx = fmaxf(mx, __shfl_xor(mx, 4, 64));
            mx = fmaxf(mx, __shfl_xor(mx, 8, 64));
            const float mnew = fmaxf(mrow[r], mx);
            const float rescale = __expf(mrow[r] - mnew);
            mrow[r] = mnew;
            float pv[4], ssum = 0.f;
#pragma unroll
            for (int j = 0; j < 4; ++j) {
                pv[j] = __expf(sf[j][r] - mnew);
                ssum += pv[j];
            }
            ssum += __shfl_xor(ssum, 1, 64);
            ssum += __shfl_xor(ssum, 2, 64);
            ssum += __shfl_xor(ssum, 4, 64);
            ssum += __shfl_xor(ssum, 8, 64);
            lrow[r] = lrow[r] * rescale + ssum;
#pragma unroll
            for (int n = 0; n < 16; ++n) o[n][r] *= rescale;
#pragma unroll
            for (int j = 0; j < 4; ++j)
                Ps[wave][(quad * 4 + r) * 72 + j * 16 + l16] = f2h(pv[j]);
        }

        // PV: O[16q][256d] += P[16q][64k] * V[64k][256d]
        __builtin_amdgcn_s_setprio(1);
#pragma unroll
        for (int s2 = 0; s2 < 2; ++s2) {
            half8 pa = *(const half8*)(&Ps[wave][l16 * 72 + s2 * 32 + quad * 8]);
#pragma unroll
            for (int n = 0; n < 16; ++n) {
                half8 vb = *(const half8*)(&Vs[(n * 16 + l16) * 64 +
                                               ((s2 * 32 + quad * 8) ^ ((l16 & 7) << 3))]);
                o[n] = __builtin_amdgcn_mfma_f32_16x16x32_f16(pa, vb, o[n], 0, 0, 0);
            }
        }
        __builtin_amdgcn_s_setprio(0);
    }

    // epilogue: row = q0+wave*16+quad*4+r, col = h*HD + n*16 + l16
#pragma unroll
    for (int r = 0; r < 4; ++r) {
        const float inv = 1.0f / lrow[r];
        const size_t base = (size_t)(b * SEQ + q0 + wave * 16 + quad * 4 + r) * QD + h * HD + l16;
#pragma unroll
        for (int n = 0; n < 16; ++n)
            O[base + n * 16] = f2h(o[n][r] * inv);
    }
}

// ---------------------------------------------------------------------------
// Workspace plan (ws proven >= 100,663,296 B by previous rounds):
//   ws[ 0,32M)  Qb (qkv gemm..attn); then Woh f16 23.07M (after attn)
//   ws[32,48M)  Kb
//   ws[48,64M)  Vt (V^T [2048][4096])
//   ws[64,96M)  Xh f16 23.07M (dead after qkv gemm) -> then Ob (attn out)
//   d_out (46,137,344 B): Wqkv f16 [8192][2816] = exactly out_size; dead
//   before the final gemm overwrites d_out.
// ---------------------------------------------------------------------------
extern "C" void kernel_launch(void* const* d_in, const int* in_sizes, int n_in,
                              void* d_out, int out_size, void* d_ws, size_t ws_size,
                              hipStream_t stream) {
    const float* X    = (const float*)d_in[0];   // (2,2048,2816) f32
    const float* Wq   = (const float*)d_in[1];   // (4096,2816) f32
    const float* Wk   = (const float*)d_in[2];   // (2048,2816) f32
    const float* Wv   = (const float*)d_in[3];   // (2048,2816) f32
    const float* Wo   = (const float*)d_in[4];   // (2816,4096) f32
    const float* qw   = (const float*)d_in[5];   // (256,) f32
    const float* kw   = (const float*)d_in[6];   // (256,) f32
    const float* cosp = (const float*)d_in[7];   // (2,2048,256) f32
    const float* sinp = (const float*)d_in[8];   // (2,2048,256) f32

    char* ws = (char*)d_ws;
    u16* Qb  = (u16*)(ws);                        // 32 MB
    u16* Kb  = (u16*)(ws + (size_t)33554432);     // 16 MB
    u16* Vt  = (u16*)(ws + (size_t)50331648);     // V^T 16 MB
    u16* Xh  = (u16*)(ws + (size_t)67108864);     // 23.07 MB, dead after qkv
    u16* Ob  = (u16*)(ws + (size_t)67108864);     // 32 MB (attn output)
    u16* Woh = (u16*)(ws);                        // 23.07 MB, after attn

    u16* Wqkv = (u16*)d_out;                      // [8192][2816] f16 = 46.14 MB

    const dim3 blk(256);
    f32_to_f16<<<dim3(5632), blk, 0, stream>>>(X,  Xh, 11534336 / 8);
    f32_to_f16<<<dim3(5632), blk, 0, stream>>>(Wq, Wqkv, 11534336 / 8);
    f32_to_f16<<<dim3(2816), blk, 0, stream>>>(Wk, Wqkv + (size_t)4096 * 2816, 5767168 / 8);
    f32_to_f16<<<dim3(2816), blk, 0, stream>>>(Wv, Wqkv + (size_t)6144 * 2816, 5767168 / 8);
    // QKV: M=4096 (16 m-tiles), N=8192 (64 n-tiles), K=2816 -> 1024 blocks
    gemm_db<0><<<dim3(1024), dim3(512), 0, stream>>>(Xh, Wqkv, Qb, Kb, Vt, 8192, 2816, 64);
    norm_rope_kernel<<<dim3((BATCH * SEQ * 32) / 4), blk, 0, stream>>>(Qb, Kb, qw, kw, cosp, sinp);
    vnorm_kernel<<<dim3(TOKS / 256, NKV), blk, 0, stream>>>(Vt);
    attn_mfma<<<dim3(SEQ / QBLK, NH, BATCH), blk, 0, stream>>>(Qb, Kb, Vt, Ob);
    f32_to_f16<<<dim3(5632), blk, 0, stream>>>(Wo, Woh, 11534336 / 8);
    // O-proj: M=4096 (16 m-tiles), N=2816 (22 n-tiles), K=4096 -> 352 blocks
    gemm_db<1><<<dim3(352), dim3(512), 0, stream>>>(Ob, Woh, d_out, nullptr, nullptr, 2816, 4096, 22);
}